// Round 7
// baseline (1041.129 us; speedup 1.0000x reference)
//
#include <hip/hip_runtime.h>
#include <math.h>

#define N_NODES 50000
#define N_TILES 3125      // N_NODES / 16 exactly
#define N_EDGES 1600000
#define F_IN 128
#define C 64
#define EF 64
#define N_GRAPHS 512
#define MLP_DIM 128
#define N_CLASSES 10
#define EPS 1e-5f
#define NB 196            // coarse buckets: dst>>8, 256 nodes each
#define CAPB 16384        // fixed bucket capacity (mean 8192, std ~90 -> safe)
#define CHUNK 4096        // edges per pass-1 block
#define NPASS1 391        // ceil(N_EDGES / CHUNK)
#define NFC0 782          // fc0 / ab MFMA blocks
#define NSLICE 8          // bn-stat atomic slices
#define EDGE_GRID 2048
#define SSTAGE 12288      // sort2 LDS staging capacity (24KB); total ~10.1K typ, 6-sigma safe

typedef __attribute__((ext_vector_type(8))) _Float16 half8;
typedef __attribute__((ext_vector_type(2))) _Float16 half2v;
typedef __attribute__((ext_vector_type(4))) float floatx4;
typedef __attribute__((ext_vector_type(4))) unsigned uintx4;

union Uh { uintx4 v; half2v h[4]; half8 h8; };

__device__ __forceinline__ unsigned short f2h(float a) {
    union { _Float16 f; unsigned short u; } c;
    c.f = (_Float16)a;   // RNE
    return c.u;
}
__device__ __forceinline__ float h2f(unsigned short u) {
    union { unsigned short u; _Float16 f; } c;
    c.u = u;
    return (float)c.f;
}
__device__ __forceinline__ half2v pk2(float a, float b) {
    auto t = __builtin_amdgcn_cvt_pkrtz(a, b);   // __fp16 vec2 -> bit-cast (R6 lesson)
    union { decltype(t) i; half2v o; } c;
    c.i = t;
    return c.o;
}

// ============ FUSED: pass1 (blocks 0..NPASS1-1) + fc0 MFMA (blocks NPASS1..) ============
__global__ __launch_bounds__(256, 3) void fc0_pass1_kernel(
        const int* __restrict__ src, const int* __restrict__ dst,
        int* __restrict__ gcur, unsigned* __restrict__ keys,
        const float* __restrict__ x, const float* __restrict__ w,
        const float* __restrict__ b, unsigned short* __restrict__ h0,
        float* __restrict__ bns) {
    __shared__ int lcnt[NB], lbase[NB], lcnt2[NB];
    __shared__ float bl1[4][64], bl2[4][64];
    int tid = threadIdx.x;

    if (blockIdx.x < NPASS1) {
        // ---------------- pass1: bin edges into fixed-capacity buckets ----------------
        int e0 = blockIdx.x * CHUNK;
        unsigned k[CHUNK / 256];
        int bk[CHUNK / 256];
        for (int i = tid; i < NB; i += 256) lcnt[i] = 0;
        __syncthreads();
#pragma unroll
        for (int i = 0; i < CHUNK / 256; i++) {
            int e = e0 + i * 256 + tid;
            if (e < N_EDGES) {
                int d = dst[e];
                k[i] = ((unsigned)d << 16) | (unsigned)src[e];
                bk[i] = d >> 8;
                atomicAdd(&lcnt[bk[i]], 1);
            } else bk[i] = -1;
        }
        __syncthreads();
        for (int i = tid; i < NB; i += 256) {
            int c = lcnt[i];
            lbase[i] = c ? atomicAdd(&gcur[i], c) : 0;
            lcnt2[i] = 0;
        }
        __syncthreads();
#pragma unroll
        for (int i = 0; i < CHUNK / 256; i++) {
            if (bk[i] >= 0) {
                int r = atomicAdd(&lcnt2[bk[i]], 1);
                keys[(size_t)bk[i] * CAPB + lbase[bk[i]] + r] = k[i];
            }
        }
        return;
    }

    // ---------------- fc0: h0[16-node tile] = x @ fc0_w + b (f16) + BN stats ----------------
    int bid = blockIdx.x - NPASS1;
    int lane = tid & 63, wid = tid >> 6;
    int q = lane >> 4, cl = lane & 15, kq = q * 8;

    Uh wf[4][4];
#pragma unroll
    for (int kh = 0; kh < 4; kh++)
#pragma unroll
        for (int cb = 0; cb < 4; cb++)
#pragma unroll
            for (int j = 0; j < 4; j++) {
                int k0 = kh * 32 + kq + 2 * j;
                int col = cb * 16 + cl;
                wf[kh][cb].h[j] = pk2(w[k0 * 64 + col], w[(k0 + 1) * 64 + col]);
            }
    float bv[4];
#pragma unroll
    for (int cb = 0; cb < 4; cb++) bv[cb] = b[cb * 16 + cl];
    float s1[4] = {0, 0, 0, 0}, s2[4] = {0, 0, 0, 0};

    for (int t = bid * 4 + wid; t < N_TILES; t += NFC0 * 4) {
        int nb = t * 16;
        floatx4 acc[4] = {{0,0,0,0},{0,0,0,0},{0,0,0,0},{0,0,0,0}};
#pragma unroll
        for (int kh = 0; kh < 4; kh++) {
            const float* xr = x + (size_t)(nb + cl) * F_IN + kh * 32 + kq;
            floatx4 xa = *(const floatx4*)xr;
            floatx4 xb = *(const floatx4*)(xr + 4);
            Uh xf;
            xf.h[0] = pk2(xa.x, xa.y); xf.h[1] = pk2(xa.z, xa.w);
            xf.h[2] = pk2(xb.x, xb.y); xf.h[3] = pk2(xb.z, xb.w);
#pragma unroll
            for (int cb = 0; cb < 4; cb++)
                acc[cb] = __builtin_amdgcn_mfma_f32_16x16x32_f16(xf.h8, wf[kh][cb].h8, acc[cb], 0, 0, 0);
        }
#pragma unroll
        for (int cb = 0; cb < 4; cb++)
#pragma unroll
            for (int r = 0; r < 4; r++) {
                float v = acc[cb][r] + bv[cb];            // node = nb+q*4+r, col = cb*16+cl
                h0[(size_t)(nb + q * 4 + r) * 64 + cb * 16 + cl] = f2h(v);
                s1[cb] += v; s2[cb] += v * v;
            }
    }
#pragma unroll
    for (int cb = 0; cb < 4; cb++) {
        s1[cb] += __shfl_xor(s1[cb], 16); s1[cb] += __shfl_xor(s1[cb], 32);
        s2[cb] += __shfl_xor(s2[cb], 16); s2[cb] += __shfl_xor(s2[cb], 32);
    }
    if (lane < 16) {
#pragma unroll
        for (int cb = 0; cb < 4; cb++) { bl1[wid][cb * 16 + lane] = s1[cb]; bl2[wid][cb * 16 + lane] = s2[cb]; }
    }
    __syncthreads();
    if (tid < 64) {
        float a  = bl1[0][tid] + bl1[1][tid] + bl1[2][tid] + bl1[3][tid];
        float c2 = bl2[0][tid] + bl2[1][tid] + bl2[2][tid] + bl2[3][tid];
        int sl = bid & (NSLICE - 1);
        atomicAdd(&bns[sl * 128 + tid], a);
        atomicAdd(&bns[sl * 128 + 64 + tid], c2);
    }
}

// ============ ab body (device): A = bn(h)@WA + cA, B = bn(h)@WB + cB (both f16) ============
__device__ __forceinline__ void ab_body(int bid, int tid,
                                        const unsigned short* __restrict__ h,
                                        const float* __restrict__ bns,
                                        const float* __restrict__ g,
                                        const float* __restrict__ bb,
                                        const float* __restrict__ w1,
                                        const float* __restrict__ b1,
                                        unsigned short* __restrict__ A,
                                        unsigned short* __restrict__ Bb,
                                        float* scale, float* shift, float* cab) {
    int lane = tid & 63, wid = tid >> 6;
    int q = lane >> 4, cl = lane & 15, kq = q * 8;

    if (tid < 64) {
        float s1v = 0.f, s2v = 0.f;
#pragma unroll
        for (int s = 0; s < NSLICE; s++) { s1v += bns[s * 128 + tid]; s2v += bns[s * 128 + 64 + tid]; }
        float mu  = s1v * (1.0f / N_NODES);
        float var = s2v * (1.0f / N_NODES) - mu * mu;
        float sc  = g[tid] * rsqrtf(var + EPS);
        scale[tid] = sc;
        shift[tid] = bb[tid] - mu * sc;
    }
    __syncthreads();
    if (tid < 128) {
        int j = tid & 63;
        float acc = (tid < 64) ? b1[j] : 0.f;
        for (int k = 0; k < 64; k++) {
            float wa_ = w1[k * EF + j], wb_ = w1[(64 + k) * EF + j];
            acc = fmaf(shift[k], (tid < 64) ? (wa_ - wb_) : wb_, acc);
        }
        cab[tid] = acc;
    }
    Uh wa[2][4], wb[2][4];
#pragma unroll
    for (int kh = 0; kh < 2; kh++)
#pragma unroll
        for (int cb = 0; cb < 4; cb++)
#pragma unroll
            for (int j = 0; j < 4; j++) {
                int k0 = kh * 32 + kq + 2 * j;
                int col = cb * 16 + cl;
                float sa = scale[k0], sb = scale[k0 + 1];
                float a0 = w1[k0 * EF + col], b0 = w1[(64 + k0) * EF + col];
                float a1 = w1[(k0 + 1) * EF + col], b1v = w1[(64 + k0 + 1) * EF + col];
                wa[kh][cb].h[j] = pk2(sa * (a0 - b0), sb * (a1 - b1v));
                wb[kh][cb].h[j] = pk2(sa * b0, sb * b1v);
            }
    __syncthreads();
    float cav[4], cbv[4];
#pragma unroll
    for (int cb = 0; cb < 4; cb++) { cav[cb] = cab[cb * 16 + cl]; cbv[cb] = cab[64 + cb * 16 + cl]; }

    for (int t = bid * 4 + wid; t < N_TILES; t += NFC0 * 4) {
        int nb = t * 16;
        const unsigned short* hrow = h + (size_t)(nb + cl) * 64 + kq;
        Uh h0f, h1f;
        h0f.v = *(const uintx4*)hrow;
        h1f.v = *(const uintx4*)(hrow + 32);
        floatx4 accA[4] = {{0,0,0,0},{0,0,0,0},{0,0,0,0},{0,0,0,0}};
        floatx4 accB[4] = {{0,0,0,0},{0,0,0,0},{0,0,0,0},{0,0,0,0}};
#pragma unroll
        for (int cb = 0; cb < 4; cb++) {
            accA[cb] = __builtin_amdgcn_mfma_f32_16x16x32_f16(h0f.h8, wa[0][cb].h8, accA[cb], 0, 0, 0);
            accB[cb] = __builtin_amdgcn_mfma_f32_16x16x32_f16(h0f.h8, wb[0][cb].h8, accB[cb], 0, 0, 0);
            accA[cb] = __builtin_amdgcn_mfma_f32_16x16x32_f16(h1f.h8, wa[1][cb].h8, accA[cb], 0, 0, 0);
            accB[cb] = __builtin_amdgcn_mfma_f32_16x16x32_f16(h1f.h8, wb[1][cb].h8, accB[cb], 0, 0, 0);
        }
#pragma unroll
        for (int cb = 0; cb < 4; cb++)
#pragma unroll
            for (int r = 0; r < 4; r++) {
                size_t o = (size_t)(nb + q * 4 + r) * 64 + cb * 16 + cl;
                A[o]  = f2h(accA[cb][r] + cav[cb]);
                Bb[o] = f2h(accB[cb][r] + cbv[cb]);
            }
    }
}

// ==== FUSED: sort-finish + ab0. LDS-staged coalesced scatter (R6, kept: fewer requests) ====
__global__ __launch_bounds__(256, 4) void sort2_ab_kernel(
        const unsigned* __restrict__ keys, const int* __restrict__ bcnt,
        int* __restrict__ cnt, int* __restrict__ gtotal,
        int* __restrict__ row_start, unsigned short* __restrict__ sorted_src,
        const unsigned short* __restrict__ h, const float* __restrict__ bns,
        const float* __restrict__ g, const float* __restrict__ bb,
        const float* __restrict__ w1, const float* __restrict__ b1,
        unsigned short* __restrict__ A, unsigned short* __restrict__ Bb) {
    __shared__ int lc[256], loc[256], lrs[256], cur[256];
    __shared__ int base;
    __shared__ float scale[64], shift[64], cab[128];
    __shared__ unsigned short sstage[SSTAGE];     // 24KB bucket staging
    int tid = threadIdx.x;
    if (blockIdx.x < NB) {
        int b = blockIdx.x;
        lc[tid] = 0;
        cur[tid] = 0;
        __syncthreads();
        int nk = bcnt[b];
        const unsigned* kb = keys + (size_t)b * CAPB;
        for (int p = tid; p < nk; p += 256)
            atomicAdd(&lc[(kb[p] >> 16) & 255], 1);
        __syncthreads();
        int node = b * 256 + tid;
        int c = lc[tid];
        if (node < N_NODES) cnt[node] = c;          // plain write — no global atomics
        int pc = (c + 15) & ~15;
        loc[tid] = pc;
        __syncthreads();
        for (int off = 1; off < 256; off <<= 1) {
            int t = (tid >= off) ? loc[tid - off] : 0;
            __syncthreads();
            loc[tid] += t;
            __syncthreads();
        }
        if (tid == 255) base = atomicAdd(gtotal, loc[255]);   // ticket: order-free CSR
        __syncthreads();
        int total = loc[255];
        int myl = loc[tid] - pc;                    // LOCAL segment start within bucket
        lrs[tid] = myl;
        if (node < N_NODES) row_start[node] = base + myl;
        __syncthreads();
        if (total <= SSTAGE) {
            // ---- fast path: LDS scatter + fill, then coalesced stream-out ----
            for (int p = tid; p < nk; p += 256) {
                unsigned k = kb[p];
                int lidx = (k >> 16) & 255;
                int r = atomicAdd(&cur[lidx], 1);
                sstage[lrs[lidx] + r] = (unsigned short)(k & 0xFFFFu);
            }
            __syncthreads();
            if (node < N_NODES && c > 0) {
                unsigned short s0 = sstage[myl];
                int pe = myl + pc;
                for (int p = myl + c; p < pe; p++) sstage[p] = s0;  // max idempotent
            }
            __syncthreads();
            // base and total are multiples of 16 -> 16B-aligned, exact uintx4 count
            uintx4* d4 = (uintx4*)(sorted_src + base);
            const uintx4* s4 = (const uintx4*)sstage;
            int n4 = total >> 3;                   // 8 ushorts per 16B
            for (int j = tid; j < n4; j += 256) d4[j] = s4[j];
        } else {
            // ---- fallback (statistically unreachable): direct global scatter ----
            for (int p = tid; p < nk; p += 256) {
                unsigned k = kb[p];
                int lidx = (k >> 16) & 255;
                int r = atomicAdd(&cur[lidx], 1);
                sorted_src[base + lrs[lidx] + r] = (unsigned short)(k & 0xFFFFu);
            }
            __syncthreads();
            if (node < N_NODES && c > 0) {
                int g0 = base + myl;
                unsigned short s0 = sorted_src[g0];
                int pe = g0 + pc;
                for (int p = g0 + c; p < pe; p++) sorted_src[p] = s0;
            }
        }
        return;
    }
    ab_body(blockIdx.x - NB, tid, h, bns, g, bb, w1, b1, A, Bb, scale, shift, cab);
}

// ============ plain ab kernel (blocks 1 and 2) ============
__global__ __launch_bounds__(256, 4) void ab_mfma_kernel(
        const unsigned short* __restrict__ h, const float* __restrict__ bns,
        const float* __restrict__ g, const float* __restrict__ bb,
        const float* __restrict__ w1, const float* __restrict__ b1,
        unsigned short* __restrict__ A, unsigned short* __restrict__ Bb) {
    __shared__ float scale[64], shift[64], cab[128];
    ab_body(blockIdx.x, threadIdx.x, h, bns, g, bb, w1, b1, A, Bb, scale, shift, cab);
}

// ============ EdgeConv: R5 coalesced-gather body + FULL residency (R7) ============
// R5 (WIN, -12%): quad-coalesced B staging, 32 req/tile. R6 post-mortem: all pipes <40%,
// OccupancyPercent 34% — capped by our own __launch_bounds__(256,4) = 16 waves/CU (50% max).
// Resources allow 2x: VGPR=64 is exactly the 8-waves/SIMD cap (512/8), LDS 18KB x 8 = 147KB
// < 160KB. R7 single variable: (256,4) -> (256,8). All 2048 blocks resident in one round
// (no 2nd-round tail), 32 waves/CU to hide the ~600cy load->ds chain.
__global__ __launch_bounds__(256, 8) void edge_mfma_kernel(
        const unsigned short* __restrict__ A, const unsigned short* __restrict__ Bb,
        const int* __restrict__ row_start, const int* __restrict__ cnt,
        const unsigned short* __restrict__ sorted_src,
        const float* __restrict__ w2, const float* __restrict__ b2,
        unsigned short* __restrict__ catp, float* __restrict__ bnsNext) {
    __shared__ float r1[4][64], r2[4][64];
    __shared__ unsigned short stage[4][2][1024];   // [wave][buf][2KB tile]
    int tid = threadIdx.x, lane = tid & 63, wid = tid >> 6;
    int q = lane >> 4;
    int cl = lane & 15;
    int kq = q * 8;

    Uh bfr[2][4];
#pragma unroll
    for (int kh = 0; kh < 2; kh++)
#pragma unroll
        for (int cb = 0; cb < 4; cb++)
#pragma unroll
            for (int j = 0; j < 4; j++) {
                _Float16 w0 = (_Float16)w2[(kh * 32 + kq + 2 * j) * 64 + cb * 16 + cl];
                _Float16 w1v = (_Float16)w2[(kh * 32 + kq + 2 * j + 1) * 64 + cb * 16 + cl];
                bfr[kh][cb].h[j] = half2v{w0, w1v};
            }
    float b2j = b2[lane];
    float s1 = 0.f, s2 = 0.f;
    const half2v zeroh = {(_Float16)0.f, (_Float16)0.f};

    // staging geometry: row held by 8 adjacent lanes, 16B chunk per lane (coalesced: 1 line/quad)
    int srow = lane >> 3;                 // 0..7 (row within 8-row group)
    int st   = lane & 7;                  // 16B chunk index
    int wswz = (st * 16) ^ (srow << 4);   // XOR swizzle within the 128B row
    int woff0 = srow * 128 + wswz;        // bytes, rows 0..7
    int woff1 = (8 + srow) * 128 + wswz;  // bytes, rows 8..15
    // fragment-read offsets (row=cl): source byte X of row stored at X^((row&7)<<4)
    int rswz  = (cl & 7) << 4;
    int roff0 = cl * 128 + ((q * 16) ^ rswz);
    int roff1 = cl * 128 + ((64 + q * 16) ^ rswz);

    char* mystage0 = (char*)&stage[wid][0][0];
    char* mystage1 = (char*)&stage[wid][1][0];

    for (int n = blockIdx.x * 4 + wid; n < N_NODES; n += gridDim.x * 4) {
        int beg = row_start[n];
        int end = beg + ((cnt[n] + 15) & ~15);
        const unsigned short* arow = A + (size_t)n * 64 + kq;
        Uh a0u, a1u;
        a0u.v = *(const uintx4*)(arow);
        a1u.v = *(const uintx4*)(arow + 32);
        floatx4 rmax0 = {-INFINITY, -INFINITY, -INFINITY, -INFINITY};
        floatx4 rmax1 = rmax0, rmax2 = rmax0, rmax3 = rmax0;

        auto stageTile = [&](int p, char* sb) {
            int s0 = (int)sorted_src[p + srow];          // 8 lanes same addr -> broadcast
            int s1v = (int)sorted_src[p + 8 + srow];
            uintx4 v0 = *(const uintx4*)(Bb + (size_t)s0 * 64 + st * 8);
            uintx4 v1 = *(const uintx4*)(Bb + (size_t)s1v * 64 + st * 8);
            *(uintx4*)(sb + woff0) = v0;
            *(uintx4*)(sb + woff1) = v1;
        };
        auto tileLds = [&](const char* sb) {
            Uh b0u, b1u, f0, f1;
            b0u.v = *(const uintx4*)(sb + roff0);
            b1u.v = *(const uintx4*)(sb + roff1);
#pragma unroll
            for (int j = 0; j < 4; j++) {      // v_pk_add_f16 + v_pk_max_f16
                f0.h[j] = __builtin_elementwise_max(a0u.h[j] + b0u.h[j], zeroh);
                f1.h[j] = __builtin_elementwise_max(a1u.h[j] + b1u.h[j], zeroh);
            }
            floatx4 acc0 = {0.f, 0.f, 0.f, 0.f}, acc1 = acc0, acc2 = acc0, acc3 = acc0;
            acc0 = __builtin_amdgcn_mfma_f32_16x16x32_f16(f0.h8, bfr[0][0].h8, acc0, 0, 0, 0);
            acc1 = __builtin_amdgcn_mfma_f32_16x16x32_f16(f0.h8, bfr[0][1].h8, acc1, 0, 0, 0);
            acc2 = __builtin_amdgcn_mfma_f32_16x16x32_f16(f0.h8, bfr[0][2].h8, acc2, 0, 0, 0);
            acc3 = __builtin_amdgcn_mfma_f32_16x16x32_f16(f0.h8, bfr[0][3].h8, acc3, 0, 0, 0);
            acc0 = __builtin_amdgcn_mfma_f32_16x16x32_f16(f1.h8, bfr[1][0].h8, acc0, 0, 0, 0);
            acc1 = __builtin_amdgcn_mfma_f32_16x16x32_f16(f1.h8, bfr[1][1].h8, acc1, 0, 0, 0);
            acc2 = __builtin_amdgcn_mfma_f32_16x16x32_f16(f1.h8, bfr[1][2].h8, acc2, 0, 0, 0);
            acc3 = __builtin_amdgcn_mfma_f32_16x16x32_f16(f1.h8, bfr[1][3].h8, acc3, 0, 0, 0);
            rmax0 = __builtin_elementwise_max(rmax0, acc0);
            rmax1 = __builtin_elementwise_max(rmax1, acc1);
            rmax2 = __builtin_elementwise_max(rmax2, acc2);
            rmax3 = __builtin_elementwise_max(rmax3, acc3);
        };

        int p0 = beg;
        for (; p0 + 32 <= end; p0 += 32) {   // two tiles per iter: both staged loads in flight
            stageTile(p0, mystage0);
            stageTile(p0 + 16, mystage1);
            tileLds(mystage0);
            tileLds(mystage1);
        }
        if (p0 < end) {                       // odd-tile remainder
            stageTile(p0, mystage0);
            tileLds(mystage0);
        }

        float v0 = fmaxf(fmaxf(rmax0.x, rmax0.y), fmaxf(rmax0.z, rmax0.w));
        float v1 = fmaxf(fmaxf(rmax1.x, rmax1.y), fmaxf(rmax1.z, rmax1.w));
        float v2 = fmaxf(fmaxf(rmax2.x, rmax2.y), fmaxf(rmax2.z, rmax2.w));
        float v3 = fmaxf(fmaxf(rmax3.x, rmax3.y), fmaxf(rmax3.z, rmax3.w));
        v0 = fmaxf(v0, __shfl_xor(v0, 16)); v0 = fmaxf(v0, __shfl_xor(v0, 32));
        v1 = fmaxf(v1, __shfl_xor(v1, 16)); v1 = fmaxf(v1, __shfl_xor(v1, 32));
        v2 = fmaxf(v2, __shfl_xor(v2, 16)); v2 = fmaxf(v2, __shfl_xor(v2, 32));
        v3 = fmaxf(v3, __shfl_xor(v3, 16)); v3 = fmaxf(v3, __shfl_xor(v3, 32));
        float vs = (lane & 32) ? ((lane & 16) ? v3 : v2) : ((lane & 16) ? v1 : v0);
        float v = fmaxf(vs + b2j, 0.f);  // -inf (empty node) -> 0; folds where(isfinite)+relu
        catp[(size_t)n * 64 + lane] = f2h(v);
        s1 += v; s2 += v * v;
    }

    if (bnsNext) {
        r1[wid][lane] = s1; r2[wid][lane] = s2;
        __syncthreads();
        if (tid < 64) {
            float a  = r1[0][tid] + r1[1][tid] + r1[2][tid] + r1[3][tid];
            float c2 = r2[0][tid] + r2[1][tid] + r2[2][tid] + r2[3][tid];
            int sl = blockIdx.x & (NSLICE - 1);
            atomicAdd(&bnsNext[sl * 128 + tid], a);
            atomicAdd(&bnsNext[sl * 128 + 64 + tid], c2);
        }
    }
}

// ============================ fused graph mean pool + MLP head + log_softmax ============================
__global__ __launch_bounds__(192) void poolhead_kernel(const unsigned short* __restrict__ cat0,
                                                       const unsigned short* __restrict__ cat1,
                                                       const unsigned short* __restrict__ cat2,
                                                       const int* __restrict__ batch,
                                                       const float* __restrict__ fc1w,
                                                       const float* __restrict__ fc1b,
                                                       const float* __restrict__ fc2w,
                                                       const float* __restrict__ fc2b,
                                                       float* __restrict__ out) {
    __shared__ int se[2];
    __shared__ float p[192];
    __shared__ float hid[128];
    __shared__ float z[10];
    __shared__ float lse;
    int g = blockIdx.x, tid = threadIdx.x;  // 192 threads
    if (tid < 2) {
        int target = g + tid;
        int lo = 0, hi = N_NODES;
        while (lo < hi) { int mid = (lo + hi) >> 1; if (batch[mid] < target) lo = mid + 1; else hi = mid; }
        se[tid] = lo;
    }
    __syncthreads();
    int s = se[0], e = se[1];
    const unsigned short* plane = (tid < 64) ? cat0 : ((tid < 128) ? cat1 : cat2);
    int col = tid & 63;
    float a0 = 0.f, a1 = 0.f, a2 = 0.f, a3 = 0.f;   // 4-way ILP in the pooling loop
    int r = s;
    for (; r + 4 <= e; r += 4) {
        a0 += h2f(plane[(size_t)(r + 0) * 64 + col]);
        a1 += h2f(plane[(size_t)(r + 1) * 64 + col]);
        a2 += h2f(plane[(size_t)(r + 2) * 64 + col]);
        a3 += h2f(plane[(size_t)(r + 3) * 64 + col]);
    }
    for (; r < e; r++) a0 += h2f(plane[(size_t)r * 64 + col]);
    float acc = (a0 + a1) + (a2 + a3);
    float denom = (e > s) ? (float)(e - s) : 1.0f;
    p[tid] = acc / denom;
    __syncthreads();
    if (tid < MLP_DIM) {
        float a = fc1b[tid];
        for (int k = 0; k < 192; k++) a = fmaf(p[k], fc1w[k * 128 + tid], a);
        hid[tid] = fmaxf(a, 0.f);
    }
    __syncthreads();
    if (tid < N_CLASSES) {
        float a = fc2b[tid];
        for (int k = 0; k < 128; k++) a = fmaf(hid[k], fc2w[k * 10 + tid], a);
        z[tid] = a;
    }
    __syncthreads();
    if (tid == 0) {
        float m = z[0];
        for (int i = 1; i < 10; i++) m = fmaxf(m, z[i]);
        float sm = 0.f;
        for (int i = 0; i < 10; i++) sm += expf(z[i] - m);
        lse = m + logf(sm);
    }
    __syncthreads();
    if (tid < N_CLASSES) out[g * 10 + tid] = z[tid] - lse;
}

// ============================ launch ============================
extern "C" void kernel_launch(void* const* d_in, const int* in_sizes, int n_in,
                              void* d_out, int out_size, void* d_ws, size_t ws_size,
                              hipStream_t stream) {
    (void)in_sizes; (void)n_in; (void)out_size; (void)ws_size;
    const float* x    = (const float*)d_in[0];
    const int*   ei   = (const int*)d_in[1];
    const int*   batch= (const int*)d_in[2];
    const float* fc0w = (const float*)d_in[3];
    const float* fc0b = (const float*)d_in[4];
    const float* fc1w = (const float*)d_in[5];
    const float* fc1b = (const float*)d_in[6];
    const float* fc2w = (const float*)d_in[7];
    const float* fc2b = (const float*)d_in[8];
    const int* src = ei;
    const int* dst = ei + N_EDGES;
    float* out = (float*)d_out;

    char* w = (char*)d_ws;
    size_t off = 0;
    auto alloc = [&](size_t bytes) -> void* {
        void* p = w + off;
        off = (off + bytes + 255) & ~(size_t)255;
        return p;
    };
    const size_t MAX_PAD_EDGES = (size_t)N_EDGES + 16 * (size_t)N_NODES;

    // zeroed-every-launch block: gcur[NB] | gtotal | bns[3][NSLICE][128]
    const size_t BNS_OFF = 1280;
    const size_t ZBYTES  = BNS_OFF + 3 * NSLICE * 128 * 4;
    char* zbase = (char*)alloc(ZBYTES);
    int*   gcur   = (int*)zbase;                     // NB ints (bucket cursors = final counts)
    int*   gtotal = (int*)(zbase + 1024);            // sort2 ticket
    float* bnsAll = (float*)(zbase + BNS_OFF);       // 3 * NSLICE * 128 floats

    unsigned short* cat0 = (unsigned short*)alloc((size_t)N_NODES * 64 * 2);  // 6.4 MB/plane (f16)
    unsigned short* cat1 = (unsigned short*)alloc((size_t)N_NODES * 64 * 2);
    unsigned short* cat2 = (unsigned short*)alloc((size_t)N_NODES * 64 * 2);
    unsigned short* h0   = (unsigned short*)alloc((size_t)N_NODES * 64 * 2);
    unsigned short* Ae   = (unsigned short*)alloc((size_t)N_NODES * 64 * 2);
    unsigned short* Be   = (unsigned short*)alloc((size_t)N_NODES * 64 * 2);
    unsigned* keys = (unsigned*)alloc((size_t)NB * CAPB * 4);    // 12.85 MB
    unsigned short* sorted_src = (unsigned short*)alloc(MAX_PAD_EDGES * 2);  // 4.8 MB
    int*   cnt       = (int*)alloc((size_t)N_NODES * 4);   // plain-written in sort2
    int*   row_start = (int*)alloc((size_t)N_NODES * 4);

    (void)hipMemsetAsync(zbase, 0, ZBYTES, stream);

    // D1: pass1 + fc0 fused (independent; pass1 hides under fc0)
    fc0_pass1_kernel<<<NPASS1 + NFC0, 256, 0, stream>>>(src, dst, gcur, keys,
                                                        x, fc0w, fc0b, h0, bnsAll);
    // D2: sort-finish (hist+scan+ticket+LDS-scatter+coalesced-out) + ab(block 0) fused
    sort2_ab_kernel<<<NB + NFC0, 256, 0, stream>>>(
        keys, gcur, cnt, gtotal, row_start, sorted_src,
        h0, bnsAll,
        (const float*)d_in[9], (const float*)d_in[10],
        (const float*)d_in[11], (const float*)d_in[12], Ae, Be);

    unsigned short* planes[3] = {cat0, cat1, cat2};
    for (int blk = 0; blk < 3; blk++) {
        const float* w2 = (const float*)d_in[13 + 6 * blk];
        const float* b2 = (const float*)d_in[14 + 6 * blk];
        if (blk > 0) {
            ab_mfma_kernel<<<NFC0, 256, 0, stream>>>(
                planes[blk - 1], bnsAll + blk * NSLICE * 128,
                (const float*)d_in[9 + 6 * blk], (const float*)d_in[10 + 6 * blk],
                (const float*)d_in[11 + 6 * blk], (const float*)d_in[12 + 6 * blk], Ae, Be);
        }
        edge_mfma_kernel<<<EDGE_GRID, 256, 0, stream>>>(
            Ae, Be, row_start, cnt, sorted_src, w2, b2, planes[blk],
            (blk < 2) ? (bnsAll + (blk + 1) * NSLICE * 128) : nullptr);
    }

    poolhead_kernel<<<N_GRAPHS, 192, 0, stream>>>(cat0, cat1, cat2, batch,
                                                  fc1w, fc1b, fc2w, fc2b, out);
}

// Round 8
// 859.514 us; speedup vs baseline: 1.2113x; 1.2113x over previous
//
#include <hip/hip_runtime.h>
#include <math.h>

#define N_NODES 50000
#define N_TILES 3125      // N_NODES / 16 exactly
#define N_EDGES 1600000
#define F_IN 128
#define C 64
#define EF 64
#define N_GRAPHS 512
#define MLP_DIM 128
#define N_CLASSES 10
#define EPS 1e-5f
#define NB 196            // coarse buckets: dst>>8, 256 nodes each
#define CAPB 16384        // fixed bucket capacity (mean 8192, std ~90 -> safe)
#define CHUNK 4096        // edges per pass-1 block
#define NPASS1 391        // ceil(N_EDGES / CHUNK)
#define NFC0 782          // fc0 / ab MFMA blocks
#define NSLICE 8          // bn-stat atomic slices
#define EDGE_GRID 2048
#define SSTAGE 12288      // sort2 LDS staging capacity (24KB); total ~10.1K typ, 6-sigma safe

typedef __attribute__((ext_vector_type(8))) _Float16 half8;
typedef __attribute__((ext_vector_type(2))) _Float16 half2v;
typedef __attribute__((ext_vector_type(4))) float floatx4;
typedef __attribute__((ext_vector_type(4))) unsigned uintx4;

union Uh { uintx4 v; half2v h[4]; half8 h8; };

__device__ __forceinline__ unsigned short f2h(float a) {
    union { _Float16 f; unsigned short u; } c;
    c.f = (_Float16)a;   // RNE
    return c.u;
}
__device__ __forceinline__ float h2f(unsigned short u) {
    union { unsigned short u; _Float16 f; } c;
    c.u = u;
    return (float)c.f;
}
__device__ __forceinline__ half2v pk2(float a, float b) {
    auto t = __builtin_amdgcn_cvt_pkrtz(a, b);   // __fp16 vec2 -> bit-cast (R6 lesson)
    union { decltype(t) i; half2v o; } c;
    c.i = t;
    return c.o;
}

// ============ FUSED: pass1 (blocks 0..NPASS1-1) + fc0 MFMA (blocks NPASS1..) ============
__global__ __launch_bounds__(256, 3) void fc0_pass1_kernel(
        const int* __restrict__ src, const int* __restrict__ dst,
        int* __restrict__ gcur, unsigned* __restrict__ keys,
        const float* __restrict__ x, const float* __restrict__ w,
        const float* __restrict__ b, unsigned short* __restrict__ h0,
        float* __restrict__ bns) {
    __shared__ int lcnt[NB], lbase[NB], lcnt2[NB];
    __shared__ float bl1[4][64], bl2[4][64];
    int tid = threadIdx.x;

    if (blockIdx.x < NPASS1) {
        // ---------------- pass1: bin edges into fixed-capacity buckets ----------------
        int e0 = blockIdx.x * CHUNK;
        unsigned k[CHUNK / 256];
        int bk[CHUNK / 256];
        for (int i = tid; i < NB; i += 256) lcnt[i] = 0;
        __syncthreads();
#pragma unroll
        for (int i = 0; i < CHUNK / 256; i++) {
            int e = e0 + i * 256 + tid;
            if (e < N_EDGES) {
                int d = dst[e];
                k[i] = ((unsigned)d << 16) | (unsigned)src[e];
                bk[i] = d >> 8;
                atomicAdd(&lcnt[bk[i]], 1);
            } else bk[i] = -1;
        }
        __syncthreads();
        for (int i = tid; i < NB; i += 256) {
            int c = lcnt[i];
            lbase[i] = c ? atomicAdd(&gcur[i], c) : 0;
            lcnt2[i] = 0;
        }
        __syncthreads();
#pragma unroll
        for (int i = 0; i < CHUNK / 256; i++) {
            if (bk[i] >= 0) {
                int r = atomicAdd(&lcnt2[bk[i]], 1);
                keys[(size_t)bk[i] * CAPB + lbase[bk[i]] + r] = k[i];
            }
        }
        return;
    }

    // ---------------- fc0: h0[16-node tile] = x @ fc0_w + b (f16) + BN stats ----------------
    int bid = blockIdx.x - NPASS1;
    int lane = tid & 63, wid = tid >> 6;
    int q = lane >> 4, cl = lane & 15, kq = q * 8;

    Uh wf[4][4];
#pragma unroll
    for (int kh = 0; kh < 4; kh++)
#pragma unroll
        for (int cb = 0; cb < 4; cb++)
#pragma unroll
            for (int j = 0; j < 4; j++) {
                int k0 = kh * 32 + kq + 2 * j;
                int col = cb * 16 + cl;
                wf[kh][cb].h[j] = pk2(w[k0 * 64 + col], w[(k0 + 1) * 64 + col]);
            }
    float bv[4];
#pragma unroll
    for (int cb = 0; cb < 4; cb++) bv[cb] = b[cb * 16 + cl];
    float s1[4] = {0, 0, 0, 0}, s2[4] = {0, 0, 0, 0};

    for (int t = bid * 4 + wid; t < N_TILES; t += NFC0 * 4) {
        int nb = t * 16;
        floatx4 acc[4] = {{0,0,0,0},{0,0,0,0},{0,0,0,0},{0,0,0,0}};
#pragma unroll
        for (int kh = 0; kh < 4; kh++) {
            const float* xr = x + (size_t)(nb + cl) * F_IN + kh * 32 + kq;
            floatx4 xa = *(const floatx4*)xr;
            floatx4 xb = *(const floatx4*)(xr + 4);
            Uh xf;
            xf.h[0] = pk2(xa.x, xa.y); xf.h[1] = pk2(xa.z, xa.w);
            xf.h[2] = pk2(xb.x, xb.y); xf.h[3] = pk2(xb.z, xb.w);
#pragma unroll
            for (int cb = 0; cb < 4; cb++)
                acc[cb] = __builtin_amdgcn_mfma_f32_16x16x32_f16(xf.h8, wf[kh][cb].h8, acc[cb], 0, 0, 0);
        }
#pragma unroll
        for (int cb = 0; cb < 4; cb++)
#pragma unroll
            for (int r = 0; r < 4; r++) {
                float v = acc[cb][r] + bv[cb];            // node = nb+q*4+r, col = cb*16+cl
                h0[(size_t)(nb + q * 4 + r) * 64 + cb * 16 + cl] = f2h(v);
                s1[cb] += v; s2[cb] += v * v;
            }
    }
#pragma unroll
    for (int cb = 0; cb < 4; cb++) {
        s1[cb] += __shfl_xor(s1[cb], 16); s1[cb] += __shfl_xor(s1[cb], 32);
        s2[cb] += __shfl_xor(s2[cb], 16); s2[cb] += __shfl_xor(s2[cb], 32);
    }
    if (lane < 16) {
#pragma unroll
        for (int cb = 0; cb < 4; cb++) { bl1[wid][cb * 16 + lane] = s1[cb]; bl2[wid][cb * 16 + lane] = s2[cb]; }
    }
    __syncthreads();
    if (tid < 64) {
        float a  = bl1[0][tid] + bl1[1][tid] + bl1[2][tid] + bl1[3][tid];
        float c2 = bl2[0][tid] + bl2[1][tid] + bl2[2][tid] + bl2[3][tid];
        int sl = bid & (NSLICE - 1);
        atomicAdd(&bns[sl * 128 + tid], a);
        atomicAdd(&bns[sl * 128 + 64 + tid], c2);
    }
}

// ============ ab body (device): A = bn(h)@WA + cA, B = bn(h)@WB + cB (both f16) ============
__device__ __forceinline__ void ab_body(int bid, int tid,
                                        const unsigned short* __restrict__ h,
                                        const float* __restrict__ bns,
                                        const float* __restrict__ g,
                                        const float* __restrict__ bb,
                                        const float* __restrict__ w1,
                                        const float* __restrict__ b1,
                                        unsigned short* __restrict__ A,
                                        unsigned short* __restrict__ Bb,
                                        float* scale, float* shift, float* cab) {
    int lane = tid & 63, wid = tid >> 6;
    int q = lane >> 4, cl = lane & 15, kq = q * 8;

    if (tid < 64) {
        float s1v = 0.f, s2v = 0.f;
#pragma unroll
        for (int s = 0; s < NSLICE; s++) { s1v += bns[s * 128 + tid]; s2v += bns[s * 128 + 64 + tid]; }
        float mu  = s1v * (1.0f / N_NODES);
        float var = s2v * (1.0f / N_NODES) - mu * mu;
        float sc  = g[tid] * rsqrtf(var + EPS);
        scale[tid] = sc;
        shift[tid] = bb[tid] - mu * sc;
    }
    __syncthreads();
    if (tid < 128) {
        int j = tid & 63;
        float acc = (tid < 64) ? b1[j] : 0.f;
        for (int k = 0; k < 64; k++) {
            float wa_ = w1[k * EF + j], wb_ = w1[(64 + k) * EF + j];
            acc = fmaf(shift[k], (tid < 64) ? (wa_ - wb_) : wb_, acc);
        }
        cab[tid] = acc;
    }
    Uh wa[2][4], wb[2][4];
#pragma unroll
    for (int kh = 0; kh < 2; kh++)
#pragma unroll
        for (int cb = 0; cb < 4; cb++)
#pragma unroll
            for (int j = 0; j < 4; j++) {
                int k0 = kh * 32 + kq + 2 * j;
                int col = cb * 16 + cl;
                float sa = scale[k0], sb = scale[k0 + 1];
                float a0 = w1[k0 * EF + col], b0 = w1[(64 + k0) * EF + col];
                float a1 = w1[(k0 + 1) * EF + col], b1v = w1[(64 + k0 + 1) * EF + col];
                wa[kh][cb].h[j] = pk2(sa * (a0 - b0), sb * (a1 - b1v));
                wb[kh][cb].h[j] = pk2(sa * b0, sb * b1v);
            }
    __syncthreads();
    float cav[4], cbv[4];
#pragma unroll
    for (int cb = 0; cb < 4; cb++) { cav[cb] = cab[cb * 16 + cl]; cbv[cb] = cab[64 + cb * 16 + cl]; }

    for (int t = bid * 4 + wid; t < N_TILES; t += NFC0 * 4) {
        int nb = t * 16;
        const unsigned short* hrow = h + (size_t)(nb + cl) * 64 + kq;
        Uh h0f, h1f;
        h0f.v = *(const uintx4*)hrow;
        h1f.v = *(const uintx4*)(hrow + 32);
        floatx4 accA[4] = {{0,0,0,0},{0,0,0,0},{0,0,0,0},{0,0,0,0}};
        floatx4 accB[4] = {{0,0,0,0},{0,0,0,0},{0,0,0,0},{0,0,0,0}};
#pragma unroll
        for (int cb = 0; cb < 4; cb++) {
            accA[cb] = __builtin_amdgcn_mfma_f32_16x16x32_f16(h0f.h8, wa[0][cb].h8, accA[cb], 0, 0, 0);
            accB[cb] = __builtin_amdgcn_mfma_f32_16x16x32_f16(h0f.h8, wb[0][cb].h8, accB[cb], 0, 0, 0);
            accA[cb] = __builtin_amdgcn_mfma_f32_16x16x32_f16(h1f.h8, wa[1][cb].h8, accA[cb], 0, 0, 0);
            accB[cb] = __builtin_amdgcn_mfma_f32_16x16x32_f16(h1f.h8, wb[1][cb].h8, accB[cb], 0, 0, 0);
        }
#pragma unroll
        for (int cb = 0; cb < 4; cb++)
#pragma unroll
            for (int r = 0; r < 4; r++) {
                size_t o = (size_t)(nb + q * 4 + r) * 64 + cb * 16 + cl;
                A[o]  = f2h(accA[cb][r] + cav[cb]);
                Bb[o] = f2h(accB[cb][r] + cbv[cb]);
            }
    }
}

// ==== FUSED: sort-finish + ab0. LDS-staged coalesced scatter (R6, kept: fewer requests) ====
__global__ __launch_bounds__(256, 4) void sort2_ab_kernel(
        const unsigned* __restrict__ keys, const int* __restrict__ bcnt,
        int* __restrict__ cnt, int* __restrict__ gtotal,
        int* __restrict__ row_start, unsigned short* __restrict__ sorted_src,
        const unsigned short* __restrict__ h, const float* __restrict__ bns,
        const float* __restrict__ g, const float* __restrict__ bb,
        const float* __restrict__ w1, const float* __restrict__ b1,
        unsigned short* __restrict__ A, unsigned short* __restrict__ Bb) {
    __shared__ int lc[256], loc[256], lrs[256], cur[256];
    __shared__ int base;
    __shared__ float scale[64], shift[64], cab[128];
    __shared__ unsigned short sstage[SSTAGE];     // 24KB bucket staging
    int tid = threadIdx.x;
    if (blockIdx.x < NB) {
        int b = blockIdx.x;
        lc[tid] = 0;
        cur[tid] = 0;
        __syncthreads();
        int nk = bcnt[b];
        const unsigned* kb = keys + (size_t)b * CAPB;
        for (int p = tid; p < nk; p += 256)
            atomicAdd(&lc[(kb[p] >> 16) & 255], 1);
        __syncthreads();
        int node = b * 256 + tid;
        int c = lc[tid];
        if (node < N_NODES) cnt[node] = c;          // plain write — no global atomics
        int pc = (c + 15) & ~15;
        loc[tid] = pc;
        __syncthreads();
        for (int off = 1; off < 256; off <<= 1) {
            int t = (tid >= off) ? loc[tid - off] : 0;
            __syncthreads();
            loc[tid] += t;
            __syncthreads();
        }
        if (tid == 255) base = atomicAdd(gtotal, loc[255]);   // ticket: order-free CSR
        __syncthreads();
        int total = loc[255];
        int myl = loc[tid] - pc;                    // LOCAL segment start within bucket
        lrs[tid] = myl;
        if (node < N_NODES) row_start[node] = base + myl;
        __syncthreads();
        if (total <= SSTAGE) {
            // ---- fast path: LDS scatter + fill, then coalesced stream-out ----
            for (int p = tid; p < nk; p += 256) {
                unsigned k = kb[p];
                int lidx = (k >> 16) & 255;
                int r = atomicAdd(&cur[lidx], 1);
                sstage[lrs[lidx] + r] = (unsigned short)(k & 0xFFFFu);
            }
            __syncthreads();
            if (node < N_NODES && c > 0) {
                unsigned short s0 = sstage[myl];
                int pe = myl + pc;
                for (int p = myl + c; p < pe; p++) sstage[p] = s0;  // max idempotent
            }
            __syncthreads();
            // base and total are multiples of 16 -> 16B-aligned, exact uintx4 count
            uintx4* d4 = (uintx4*)(sorted_src + base);
            const uintx4* s4 = (const uintx4*)sstage;
            int n4 = total >> 3;                   // 8 ushorts per 16B
            for (int j = tid; j < n4; j += 256) d4[j] = s4[j];
        } else {
            // ---- fallback (statistically unreachable): direct global scatter ----
            for (int p = tid; p < nk; p += 256) {
                unsigned k = kb[p];
                int lidx = (k >> 16) & 255;
                int r = atomicAdd(&cur[lidx], 1);
                sorted_src[base + lrs[lidx] + r] = (unsigned short)(k & 0xFFFFu);
            }
            __syncthreads();
            if (node < N_NODES && c > 0) {
                int g0 = base + myl;
                unsigned short s0 = sorted_src[g0];
                int pe = g0 + pc;
                for (int p = g0 + c; p < pe; p++) sorted_src[p] = s0;
            }
        }
        return;
    }
    ab_body(blockIdx.x - NB, tid, h, bns, g, bb, w1, b1, A, Bb, scale, shift, cab);
}

// ============ plain ab kernel (blocks 1 and 2) ============
__global__ __launch_bounds__(256, 4) void ab_mfma_kernel(
        const unsigned short* __restrict__ h, const float* __restrict__ bns,
        const float* __restrict__ g, const float* __restrict__ bb,
        const float* __restrict__ w1, const float* __restrict__ b1,
        unsigned short* __restrict__ A, unsigned short* __restrict__ Bb) {
    __shared__ float scale[64], shift[64], cab[128];
    ab_body(blockIdx.x, threadIdx.x, h, bns, g, bb, w1, b1, A, Bb, scale, shift, cab);
}

// ============ EdgeConv: R5 coalesced-gather body + 6 blocks/CU residency (R8) ============
// R7 post-mortem: (256,8) forced VGPR cap 512/8=64 -> compiler clamped to 32 and SPILLED
// (VGPR_Count=32, FETCH 722MB, WRITE 365MB scratch traffic, 350us). Occupancy must be
// bought only up to the no-spill cap. R8: (256,6) -> cap 512/6=84 >= our 64, no spill
// (sentinel: VGPR_Count must stay 64). 24 waves/CU (75% ceiling) vs R6's 16 (50%).
// LDS 18KB x 6 = 110KB < 160KB. Single variable vs R6's 356us baseline.
__global__ __launch_bounds__(256, 6) void edge_mfma_kernel(
        const unsigned short* __restrict__ A, const unsigned short* __restrict__ Bb,
        const int* __restrict__ row_start, const int* __restrict__ cnt,
        const unsigned short* __restrict__ sorted_src,
        const float* __restrict__ w2, const float* __restrict__ b2,
        unsigned short* __restrict__ catp, float* __restrict__ bnsNext) {
    __shared__ float r1[4][64], r2[4][64];
    __shared__ unsigned short stage[4][2][1024];   // [wave][buf][2KB tile]
    int tid = threadIdx.x, lane = tid & 63, wid = tid >> 6;
    int q = lane >> 4;
    int cl = lane & 15;
    int kq = q * 8;

    Uh bfr[2][4];
#pragma unroll
    for (int kh = 0; kh < 2; kh++)
#pragma unroll
        for (int cb = 0; cb < 4; cb++)
#pragma unroll
            for (int j = 0; j < 4; j++) {
                _Float16 w0 = (_Float16)w2[(kh * 32 + kq + 2 * j) * 64 + cb * 16 + cl];
                _Float16 w1v = (_Float16)w2[(kh * 32 + kq + 2 * j + 1) * 64 + cb * 16 + cl];
                bfr[kh][cb].h[j] = half2v{w0, w1v};
            }
    float b2j = b2[lane];
    float s1 = 0.f, s2 = 0.f;
    const half2v zeroh = {(_Float16)0.f, (_Float16)0.f};

    // staging geometry: row held by 8 adjacent lanes, 16B chunk per lane (coalesced: 1 line/quad)
    int srow = lane >> 3;                 // 0..7 (row within 8-row group)
    int st   = lane & 7;                  // 16B chunk index
    int wswz = (st * 16) ^ (srow << 4);   // XOR swizzle within the 128B row
    int woff0 = srow * 128 + wswz;        // bytes, rows 0..7
    int woff1 = (8 + srow) * 128 + wswz;  // bytes, rows 8..15
    // fragment-read offsets (row=cl): source byte X of row stored at X^((row&7)<<4)
    int rswz  = (cl & 7) << 4;
    int roff0 = cl * 128 + ((q * 16) ^ rswz);
    int roff1 = cl * 128 + ((64 + q * 16) ^ rswz);

    char* mystage0 = (char*)&stage[wid][0][0];
    char* mystage1 = (char*)&stage[wid][1][0];

    for (int n = blockIdx.x * 4 + wid; n < N_NODES; n += gridDim.x * 4) {
        int beg = row_start[n];
        int end = beg + ((cnt[n] + 15) & ~15);
        const unsigned short* arow = A + (size_t)n * 64 + kq;
        Uh a0u, a1u;
        a0u.v = *(const uintx4*)(arow);
        a1u.v = *(const uintx4*)(arow + 32);
        floatx4 rmax0 = {-INFINITY, -INFINITY, -INFINITY, -INFINITY};
        floatx4 rmax1 = rmax0, rmax2 = rmax0, rmax3 = rmax0;

        auto stageTile = [&](int p, char* sb) {
            int s0 = (int)sorted_src[p + srow];          // 8 lanes same addr -> broadcast
            int s1v = (int)sorted_src[p + 8 + srow];
            uintx4 v0 = *(const uintx4*)(Bb + (size_t)s0 * 64 + st * 8);
            uintx4 v1 = *(const uintx4*)(Bb + (size_t)s1v * 64 + st * 8);
            *(uintx4*)(sb + woff0) = v0;
            *(uintx4*)(sb + woff1) = v1;
        };
        auto tileLds = [&](const char* sb) {
            Uh b0u, b1u, f0, f1;
            b0u.v = *(const uintx4*)(sb + roff0);
            b1u.v = *(const uintx4*)(sb + roff1);
#pragma unroll
            for (int j = 0; j < 4; j++) {      // v_pk_add_f16 + v_pk_max_f16
                f0.h[j] = __builtin_elementwise_max(a0u.h[j] + b0u.h[j], zeroh);
                f1.h[j] = __builtin_elementwise_max(a1u.h[j] + b1u.h[j], zeroh);
            }
            floatx4 acc0 = {0.f, 0.f, 0.f, 0.f}, acc1 = acc0, acc2 = acc0, acc3 = acc0;
            acc0 = __builtin_amdgcn_mfma_f32_16x16x32_f16(f0.h8, bfr[0][0].h8, acc0, 0, 0, 0);
            acc1 = __builtin_amdgcn_mfma_f32_16x16x32_f16(f0.h8, bfr[0][1].h8, acc1, 0, 0, 0);
            acc2 = __builtin_amdgcn_mfma_f32_16x16x32_f16(f0.h8, bfr[0][2].h8, acc2, 0, 0, 0);
            acc3 = __builtin_amdgcn_mfma_f32_16x16x32_f16(f0.h8, bfr[0][3].h8, acc3, 0, 0, 0);
            acc0 = __builtin_amdgcn_mfma_f32_16x16x32_f16(f1.h8, bfr[1][0].h8, acc0, 0, 0, 0);
            acc1 = __builtin_amdgcn_mfma_f32_16x16x32_f16(f1.h8, bfr[1][1].h8, acc1, 0, 0, 0);
            acc2 = __builtin_amdgcn_mfma_f32_16x16x32_f16(f1.h8, bfr[1][2].h8, acc2, 0, 0, 0);
            acc3 = __builtin_amdgcn_mfma_f32_16x16x32_f16(f1.h8, bfr[1][3].h8, acc3, 0, 0, 0);
            rmax0 = __builtin_elementwise_max(rmax0, acc0);
            rmax1 = __builtin_elementwise_max(rmax1, acc1);
            rmax2 = __builtin_elementwise_max(rmax2, acc2);
            rmax3 = __builtin_elementwise_max(rmax3, acc3);
        };

        int p0 = beg;
        for (; p0 + 32 <= end; p0 += 32) {   // two tiles per iter: both staged loads in flight
            stageTile(p0, mystage0);
            stageTile(p0 + 16, mystage1);
            tileLds(mystage0);
            tileLds(mystage1);
        }
        if (p0 < end) {                       // odd-tile remainder
            stageTile(p0, mystage0);
            tileLds(mystage0);
        }

        float v0 = fmaxf(fmaxf(rmax0.x, rmax0.y), fmaxf(rmax0.z, rmax0.w));
        float v1 = fmaxf(fmaxf(rmax1.x, rmax1.y), fmaxf(rmax1.z, rmax1.w));
        float v2 = fmaxf(fmaxf(rmax2.x, rmax2.y), fmaxf(rmax2.z, rmax2.w));
        float v3 = fmaxf(fmaxf(rmax3.x, rmax3.y), fmaxf(rmax3.z, rmax3.w));
        v0 = fmaxf(v0, __shfl_xor(v0, 16)); v0 = fmaxf(v0, __shfl_xor(v0, 32));
        v1 = fmaxf(v1, __shfl_xor(v1, 16)); v1 = fmaxf(v1, __shfl_xor(v1, 32));
        v2 = fmaxf(v2, __shfl_xor(v2, 16)); v2 = fmaxf(v2, __shfl_xor(v2, 32));
        v3 = fmaxf(v3, __shfl_xor(v3, 16)); v3 = fmaxf(v3, __shfl_xor(v3, 32));
        float vs = (lane & 32) ? ((lane & 16) ? v3 : v2) : ((lane & 16) ? v1 : v0);
        float v = fmaxf(vs + b2j, 0.f);  // -inf (empty node) -> 0; folds where(isfinite)+relu
        catp[(size_t)n * 64 + lane] = f2h(v);
        s1 += v; s2 += v * v;
    }

    if (bnsNext) {
        r1[wid][lane] = s1; r2[wid][lane] = s2;
        __syncthreads();
        if (tid < 64) {
            float a  = r1[0][tid] + r1[1][tid] + r1[2][tid] + r1[3][tid];
            float c2 = r2[0][tid] + r2[1][tid] + r2[2][tid] + r2[3][tid];
            int sl = blockIdx.x & (NSLICE - 1);
            atomicAdd(&bnsNext[sl * 128 + tid], a);
            atomicAdd(&bnsNext[sl * 128 + 64 + tid], c2);
        }
    }
}

// ============================ fused graph mean pool + MLP head + log_softmax ============================
__global__ __launch_bounds__(192) void poolhead_kernel(const unsigned short* __restrict__ cat0,
                                                       const unsigned short* __restrict__ cat1,
                                                       const unsigned short* __restrict__ cat2,
                                                       const int* __restrict__ batch,
                                                       const float* __restrict__ fc1w,
                                                       const float* __restrict__ fc1b,
                                                       const float* __restrict__ fc2w,
                                                       const float* __restrict__ fc2b,
                                                       float* __restrict__ out) {
    __shared__ int se[2];
    __shared__ float p[192];
    __shared__ float hid[128];
    __shared__ float z[10];
    __shared__ float lse;
    int g = blockIdx.x, tid = threadIdx.x;  // 192 threads
    if (tid < 2) {
        int target = g + tid;
        int lo = 0, hi = N_NODES;
        while (lo < hi) { int mid = (lo + hi) >> 1; if (batch[mid] < target) lo = mid + 1; else hi = mid; }
        se[tid] = lo;
    }
    __syncthreads();
    int s = se[0], e = se[1];
    const unsigned short* plane = (tid < 64) ? cat0 : ((tid < 128) ? cat1 : cat2);
    int col = tid & 63;
    float a0 = 0.f, a1 = 0.f, a2 = 0.f, a3 = 0.f;   // 4-way ILP in the pooling loop
    int r = s;
    for (; r + 4 <= e; r += 4) {
        a0 += h2f(plane[(size_t)(r + 0) * 64 + col]);
        a1 += h2f(plane[(size_t)(r + 1) * 64 + col]);
        a2 += h2f(plane[(size_t)(r + 2) * 64 + col]);
        a3 += h2f(plane[(size_t)(r + 3) * 64 + col]);
    }
    for (; r < e; r++) a0 += h2f(plane[(size_t)r * 64 + col]);
    float acc = (a0 + a1) + (a2 + a3);
    float denom = (e > s) ? (float)(e - s) : 1.0f;
    p[tid] = acc / denom;
    __syncthreads();
    if (tid < MLP_DIM) {
        float a = fc1b[tid];
        for (int k = 0; k < 192; k++) a = fmaf(p[k], fc1w[k * 128 + tid], a);
        hid[tid] = fmaxf(a, 0.f);
    }
    __syncthreads();
    if (tid < N_CLASSES) {
        float a = fc2b[tid];
        for (int k = 0; k < 128; k++) a = fmaf(hid[k], fc2w[k * 10 + tid], a);
        z[tid] = a;
    }
    __syncthreads();
    if (tid == 0) {
        float m = z[0];
        for (int i = 1; i < 10; i++) m = fmaxf(m, z[i]);
        float sm = 0.f;
        for (int i = 0; i < 10; i++) sm += expf(z[i] - m);
        lse = m + logf(sm);
    }
    __syncthreads();
    if (tid < N_CLASSES) out[g * 10 + tid] = z[tid] - lse;
}

// ============================ launch ============================
extern "C" void kernel_launch(void* const* d_in, const int* in_sizes, int n_in,
                              void* d_out, int out_size, void* d_ws, size_t ws_size,
                              hipStream_t stream) {
    (void)in_sizes; (void)n_in; (void)out_size; (void)ws_size;
    const float* x    = (const float*)d_in[0];
    const int*   ei   = (const int*)d_in[1];
    const int*   batch= (const int*)d_in[2];
    const float* fc0w = (const float*)d_in[3];
    const float* fc0b = (const float*)d_in[4];
    const float* fc1w = (const float*)d_in[5];
    const float* fc1b = (const float*)d_in[6];
    const float* fc2w = (const float*)d_in[7];
    const float* fc2b = (const float*)d_in[8];
    const int* src = ei;
    const int* dst = ei + N_EDGES;
    float* out = (float*)d_out;

    char* w = (char*)d_ws;
    size_t off = 0;
    auto alloc = [&](size_t bytes) -> void* {
        void* p = w + off;
        off = (off + bytes + 255) & ~(size_t)255;
        return p;
    };
    const size_t MAX_PAD_EDGES = (size_t)N_EDGES + 16 * (size_t)N_NODES;

    // zeroed-every-launch block: gcur[NB] | gtotal | bns[3][NSLICE][128]
    const size_t BNS_OFF = 1280;
    const size_t ZBYTES  = BNS_OFF + 3 * NSLICE * 128 * 4;
    char* zbase = (char*)alloc(ZBYTES);
    int*   gcur   = (int*)zbase;                     // NB ints (bucket cursors = final counts)
    int*   gtotal = (int*)(zbase + 1024);            // sort2 ticket
    float* bnsAll = (float*)(zbase + BNS_OFF);       // 3 * NSLICE * 128 floats

    unsigned short* cat0 = (unsigned short*)alloc((size_t)N_NODES * 64 * 2);  // 6.4 MB/plane (f16)
    unsigned short* cat1 = (unsigned short*)alloc((size_t)N_NODES * 64 * 2);
    unsigned short* cat2 = (unsigned short*)alloc((size_t)N_NODES * 64 * 2);
    unsigned short* h0   = (unsigned short*)alloc((size_t)N_NODES * 64 * 2);
    unsigned short* Ae   = (unsigned short*)alloc((size_t)N_NODES * 64 * 2);
    unsigned short* Be   = (unsigned short*)alloc((size_t)N_NODES * 64 * 2);
    unsigned* keys = (unsigned*)alloc((size_t)NB * CAPB * 4);    // 12.85 MB
    unsigned short* sorted_src = (unsigned short*)alloc(MAX_PAD_EDGES * 2);  // 4.8 MB
    int*   cnt       = (int*)alloc((size_t)N_NODES * 4);   // plain-written in sort2
    int*   row_start = (int*)alloc((size_t)N_NODES * 4);

    (void)hipMemsetAsync(zbase, 0, ZBYTES, stream);

    // D1: pass1 + fc0 fused (independent; pass1 hides under fc0)
    fc0_pass1_kernel<<<NPASS1 + NFC0, 256, 0, stream>>>(src, dst, gcur, keys,
                                                        x, fc0w, fc0b, h0, bnsAll);
    // D2: sort-finish (hist+scan+ticket+LDS-scatter+coalesced-out) + ab(block 0) fused
    sort2_ab_kernel<<<NB + NFC0, 256, 0, stream>>>(
        keys, gcur, cnt, gtotal, row_start, sorted_src,
        h0, bnsAll,
        (const float*)d_in[9], (const float*)d_in[10],
        (const float*)d_in[11], (const float*)d_in[12], Ae, Be);

    unsigned short* planes[3] = {cat0, cat1, cat2};
    for (int blk = 0; blk < 3; blk++) {
        const float* w2 = (const float*)d_in[13 + 6 * blk];
        const float* b2 = (const float*)d_in[14 + 6 * blk];
        if (blk > 0) {
            ab_mfma_kernel<<<NFC0, 256, 0, stream>>>(
                planes[blk - 1], bnsAll + blk * NSLICE * 128,
                (const float*)d_in[9 + 6 * blk], (const float*)d_in[10 + 6 * blk],
                (const float*)d_in[11 + 6 * blk], (const float*)d_in[12 + 6 * blk], Ae, Be);
        }
        edge_mfma_kernel<<<EDGE_GRID, 256, 0, stream>>>(
            Ae, Be, row_start, cnt, sorted_src, w2, b2, planes[blk],
            (blk < 2) ? (bnsAll + (blk + 1) * NSLICE * 128) : nullptr);
    }

    poolhead_kernel<<<N_GRAPHS, 192, 0, stream>>>(cat0, cat1, cat2, batch,
                                                  fc1w, fc1b, fc2w, fc2b, out);
}

// Round 9
// 438.304 us; speedup vs baseline: 2.3754x; 1.9610x over previous
//
#include <hip/hip_runtime.h>
#include <math.h>

#define N_NODES 50000
#define N_TILES 3125      // N_NODES / 16 exactly
#define N_EDGES 1600000
#define F_IN 128
#define C 64
#define EF 64
#define N_GRAPHS 512
#define MLP_DIM 128
#define N_CLASSES 10
#define EPS 1e-5f
#define NB 196            // coarse buckets: dst>>8, 256 nodes each
#define CAPB 16384        // fixed bucket capacity (mean 8192, std ~90 -> safe)
#define CHUNK 4096        // edges per pass-1 block
#define NPASS1 391        // ceil(N_EDGES / CHUNK)
#define NFC0 782          // fc0 / ab MFMA blocks
#define NSLICE 8          // bn-stat atomic slices
#define EDGE_GRID 2048
#define SSTAGE 12288      // sort2 LDS staging capacity (24KB)

typedef __attribute__((ext_vector_type(8))) _Float16 half8;
typedef __attribute__((ext_vector_type(2))) _Float16 half2v;
typedef __attribute__((ext_vector_type(4))) float floatx4;
typedef __attribute__((ext_vector_type(4))) unsigned uintx4;

union Uh { uintx4 v; half2v h[4]; half8 h8; };

__device__ __forceinline__ unsigned short f2h(float a) {
    union { _Float16 f; unsigned short u; } c;
    c.f = (_Float16)a;   // RNE
    return c.u;
}
__device__ __forceinline__ float h2f(unsigned short u) {
    union { unsigned short u; _Float16 f; } c;
    c.u = u;
    return (float)c.f;
}
__device__ __forceinline__ half2v pk2(float a, float b) {
    auto t = __builtin_amdgcn_cvt_pkrtz(a, b);   // __fp16 vec2 -> bit-cast (R6 lesson)
    union { decltype(t) i; half2v o; } c;
    c.i = t;
    return c.o;
}

// ============ FUSED: pass1 (blocks 0..NPASS1-1) + fc0 MFMA (blocks NPASS1..) ============
__global__ __launch_bounds__(256, 3) void fc0_pass1_kernel(
        const int* __restrict__ src, const int* __restrict__ dst,
        int* __restrict__ gcur, unsigned* __restrict__ keys,
        const float* __restrict__ x, const float* __restrict__ w,
        const float* __restrict__ b, unsigned short* __restrict__ h0,
        float* __restrict__ bns) {
    __shared__ int lcnt[NB], lbase[NB], lcnt2[NB];
    __shared__ float bl1[4][64], bl2[4][64];
    int tid = threadIdx.x;

    if (blockIdx.x < NPASS1) {
        // ---------------- pass1: bin edges into fixed-capacity buckets ----------------
        int e0 = blockIdx.x * CHUNK;
        unsigned k[CHUNK / 256];
        int bk[CHUNK / 256];
        for (int i = tid; i < NB; i += 256) lcnt[i] = 0;
        __syncthreads();
#pragma unroll
        for (int i = 0; i < CHUNK / 256; i++) {
            int e = e0 + i * 256 + tid;
            if (e < N_EDGES) {
                int d = dst[e];
                k[i] = ((unsigned)d << 16) | (unsigned)src[e];
                bk[i] = d >> 8;
                atomicAdd(&lcnt[bk[i]], 1);
            } else bk[i] = -1;
        }
        __syncthreads();
        for (int i = tid; i < NB; i += 256) {
            int c = lcnt[i];
            lbase[i] = c ? atomicAdd(&gcur[i], c) : 0;
            lcnt2[i] = 0;
        }
        __syncthreads();
#pragma unroll
        for (int i = 0; i < CHUNK / 256; i++) {
            if (bk[i] >= 0) {
                int r = atomicAdd(&lcnt2[bk[i]], 1);
                keys[(size_t)bk[i] * CAPB + lbase[bk[i]] + r] = k[i];
            }
        }
        return;
    }

    // ---------------- fc0: h0[16-node tile] = x @ fc0_w + b (f16) + BN stats ----------------
    int bid = blockIdx.x - NPASS1;
    int lane = tid & 63, wid = tid >> 6;
    int q = lane >> 4, cl = lane & 15, kq = q * 8;

    Uh wf[4][4];
#pragma unroll
    for (int kh = 0; kh < 4; kh++)
#pragma unroll
        for (int cb = 0; cb < 4; cb++)
#pragma unroll
            for (int j = 0; j < 4; j++) {
                int k0 = kh * 32 + kq + 2 * j;
                int col = cb * 16 + cl;
                wf[kh][cb].h[j] = pk2(w[k0 * 64 + col], w[(k0 + 1) * 64 + col]);
            }
    float bv[4];
#pragma unroll
    for (int cb = 0; cb < 4; cb++) bv[cb] = b[cb * 16 + cl];
    float s1[4] = {0, 0, 0, 0}, s2[4] = {0, 0, 0, 0};

    for (int t = bid * 4 + wid; t < N_TILES; t += NFC0 * 4) {
        int nb = t * 16;
        floatx4 acc[4] = {{0,0,0,0},{0,0,0,0},{0,0,0,0},{0,0,0,0}};
#pragma unroll
        for (int kh = 0; kh < 4; kh++) {
            const float* xr = x + (size_t)(nb + cl) * F_IN + kh * 32 + kq;
            floatx4 xa = *(const floatx4*)xr;
            floatx4 xb = *(const floatx4*)(xr + 4);
            Uh xf;
            xf.h[0] = pk2(xa.x, xa.y); xf.h[1] = pk2(xa.z, xa.w);
            xf.h[2] = pk2(xb.x, xb.y); xf.h[3] = pk2(xb.z, xb.w);
#pragma unroll
            for (int cb = 0; cb < 4; cb++)
                acc[cb] = __builtin_amdgcn_mfma_f32_16x16x32_f16(xf.h8, wf[kh][cb].h8, acc[cb], 0, 0, 0);
        }
#pragma unroll
        for (int cb = 0; cb < 4; cb++)
#pragma unroll
            for (int r = 0; r < 4; r++) {
                float v = acc[cb][r] + bv[cb];            // node = nb+q*4+r, col = cb*16+cl
                h0[(size_t)(nb + q * 4 + r) * 64 + cb * 16 + cl] = f2h(v);
                s1[cb] += v; s2[cb] += v * v;
            }
    }
#pragma unroll
    for (int cb = 0; cb < 4; cb++) {
        s1[cb] += __shfl_xor(s1[cb], 16); s1[cb] += __shfl_xor(s1[cb], 32);
        s2[cb] += __shfl_xor(s2[cb], 16); s2[cb] += __shfl_xor(s2[cb], 32);
    }
    if (lane < 16) {
#pragma unroll
        for (int cb = 0; cb < 4; cb++) { bl1[wid][cb * 16 + lane] = s1[cb]; bl2[wid][cb * 16 + lane] = s2[cb]; }
    }
    __syncthreads();
    if (tid < 64) {
        float a  = bl1[0][tid] + bl1[1][tid] + bl1[2][tid] + bl1[3][tid];
        float c2 = bl2[0][tid] + bl2[1][tid] + bl2[2][tid] + bl2[3][tid];
        int sl = bid & (NSLICE - 1);
        atomicAdd(&bns[sl * 128 + tid], a);
        atomicAdd(&bns[sl * 128 + 64 + tid], c2);
    }
}

// ============ ab body (device): A = bn(h)@WA + cA, B = bn(h)@WB + cB (both f16) ============
__device__ __forceinline__ void ab_body(int bid, int tid,
                                        const unsigned short* __restrict__ h,
                                        const float* __restrict__ bns,
                                        const float* __restrict__ g,
                                        const float* __restrict__ bb,
                                        const float* __restrict__ w1,
                                        const float* __restrict__ b1,
                                        unsigned short* __restrict__ A,
                                        unsigned short* __restrict__ Bb,
                                        float* scale, float* shift, float* cab) {
    int lane = tid & 63, wid = tid >> 6;
    int q = lane >> 4, cl = lane & 15, kq = q * 8;

    if (tid < 64) {
        float s1v = 0.f, s2v = 0.f;
#pragma unroll
        for (int s = 0; s < NSLICE; s++) { s1v += bns[s * 128 + tid]; s2v += bns[s * 128 + 64 + tid]; }
        float mu  = s1v * (1.0f / N_NODES);
        float var = s2v * (1.0f / N_NODES) - mu * mu;
        float sc  = g[tid] * rsqrtf(var + EPS);
        scale[tid] = sc;
        shift[tid] = bb[tid] - mu * sc;
    }
    __syncthreads();
    if (tid < 128) {
        int j = tid & 63;
        float acc = (tid < 64) ? b1[j] : 0.f;
        for (int k = 0; k < 64; k++) {
            float wa_ = w1[k * EF + j], wb_ = w1[(64 + k) * EF + j];
            acc = fmaf(shift[k], (tid < 64) ? (wa_ - wb_) : wb_, acc);
        }
        cab[tid] = acc;
    }
    Uh wa[2][4], wb[2][4];
#pragma unroll
    for (int kh = 0; kh < 2; kh++)
#pragma unroll
        for (int cb = 0; cb < 4; cb++)
#pragma unroll
            for (int j = 0; j < 4; j++) {
                int k0 = kh * 32 + kq + 2 * j;
                int col = cb * 16 + cl;
                float sa = scale[k0], sb = scale[k0 + 1];
                float a0 = w1[k0 * EF + col], b0 = w1[(64 + k0) * EF + col];
                float a1 = w1[(k0 + 1) * EF + col], b1v = w1[(64 + k0 + 1) * EF + col];
                wa[kh][cb].h[j] = pk2(sa * (a0 - b0), sb * (a1 - b1v));
                wb[kh][cb].h[j] = pk2(sa * b0, sb * b1v);
            }
    __syncthreads();
    float cav[4], cbv[4];
#pragma unroll
    for (int cb = 0; cb < 4; cb++) { cav[cb] = cab[cb * 16 + cl]; cbv[cb] = cab[64 + cb * 16 + cl]; }

    for (int t = bid * 4 + wid; t < N_TILES; t += NFC0 * 4) {
        int nb = t * 16;
        const unsigned short* hrow = h + (size_t)(nb + cl) * 64 + kq;
        Uh h0f, h1f;
        h0f.v = *(const uintx4*)hrow;
        h1f.v = *(const uintx4*)(hrow + 32);
        floatx4 accA[4] = {{0,0,0,0},{0,0,0,0},{0,0,0,0},{0,0,0,0}};
        floatx4 accB[4] = {{0,0,0,0},{0,0,0,0},{0,0,0,0},{0,0,0,0}};
#pragma unroll
        for (int cb = 0; cb < 4; cb++) {
            accA[cb] = __builtin_amdgcn_mfma_f32_16x16x32_f16(h0f.h8, wa[0][cb].h8, accA[cb], 0, 0, 0);
            accB[cb] = __builtin_amdgcn_mfma_f32_16x16x32_f16(h0f.h8, wb[0][cb].h8, accB[cb], 0, 0, 0);
            accA[cb] = __builtin_amdgcn_mfma_f32_16x16x32_f16(h1f.h8, wa[1][cb].h8, accA[cb], 0, 0, 0);
            accB[cb] = __builtin_amdgcn_mfma_f32_16x16x32_f16(h1f.h8, wb[1][cb].h8, accB[cb], 0, 0, 0);
        }
#pragma unroll
        for (int cb = 0; cb < 4; cb++)
#pragma unroll
            for (int r = 0; r < 4; r++) {
                size_t o = (size_t)(nb + q * 4 + r) * 64 + cb * 16 + cl;
                A[o]  = f2h(accA[cb][r] + cav[cb]);
                Bb[o] = f2h(accB[cb][r] + cbv[cb]);
            }
    }
}

// ==== FUSED: sort-finish + ab0. LDS-staged coalesced scatter (R6, kept) ====
__global__ __launch_bounds__(256, 4) void sort2_ab_kernel(
        const unsigned* __restrict__ keys, const int* __restrict__ bcnt,
        int* __restrict__ cnt, int* __restrict__ gtotal,
        int* __restrict__ row_start, unsigned short* __restrict__ sorted_src,
        const unsigned short* __restrict__ h, const float* __restrict__ bns,
        const float* __restrict__ g, const float* __restrict__ bb,
        const float* __restrict__ w1, const float* __restrict__ b1,
        unsigned short* __restrict__ A, unsigned short* __restrict__ Bb) {
    __shared__ int lc[256], loc[256], lrs[256], cur[256];
    __shared__ int base;
    __shared__ float scale[64], shift[64], cab[128];
    __shared__ unsigned short sstage[SSTAGE];     // 24KB bucket staging
    int tid = threadIdx.x;
    if (blockIdx.x < NB) {
        int b = blockIdx.x;
        lc[tid] = 0;
        cur[tid] = 0;
        __syncthreads();
        int nk = bcnt[b];
        const unsigned* kb = keys + (size_t)b * CAPB;
        for (int p = tid; p < nk; p += 256)
            atomicAdd(&lc[(kb[p] >> 16) & 255], 1);
        __syncthreads();
        int node = b * 256 + tid;
        int c = lc[tid];
        if (node < N_NODES) cnt[node] = c;          // plain write — no global atomics
        int pc = (c + 15) & ~15;
        loc[tid] = pc;
        __syncthreads();
        for (int off = 1; off < 256; off <<= 1) {
            int t = (tid >= off) ? loc[tid - off] : 0;
            __syncthreads();
            loc[tid] += t;
            __syncthreads();
        }
        if (tid == 255) base = atomicAdd(gtotal, loc[255]);   // ticket: order-free CSR
        __syncthreads();
        int total = loc[255];
        int myl = loc[tid] - pc;                    // LOCAL segment start within bucket
        lrs[tid] = myl;
        if (node < N_NODES) row_start[node] = base + myl;
        __syncthreads();
        if (total <= SSTAGE) {
            // ---- fast path: LDS scatter + fill, then coalesced stream-out ----
            for (int p = tid; p < nk; p += 256) {
                unsigned k = kb[p];
                int lidx = (k >> 16) & 255;
                int r = atomicAdd(&cur[lidx], 1);
                sstage[lrs[lidx] + r] = (unsigned short)(k & 0xFFFFu);
            }
            __syncthreads();
            if (node < N_NODES && c > 0) {
                unsigned short s0 = sstage[myl];
                int pe = myl + pc;
                for (int p = myl + c; p < pe; p++) sstage[p] = s0;  // max idempotent
            }
            __syncthreads();
            uintx4* d4 = (uintx4*)(sorted_src + base);
            const uintx4* s4 = (const uintx4*)sstage;
            int n4 = total >> 3;                   // 8 ushorts per 16B
            for (int j = tid; j < n4; j += 256) d4[j] = s4[j];
        } else {
            // ---- fallback (statistically unreachable): direct global scatter ----
            for (int p = tid; p < nk; p += 256) {
                unsigned k = kb[p];
                int lidx = (k >> 16) & 255;
                int r = atomicAdd(&cur[lidx], 1);
                sorted_src[base + lrs[lidx] + r] = (unsigned short)(k & 0xFFFFu);
            }
            __syncthreads();
            if (node < N_NODES && c > 0) {
                int g0 = base + myl;
                unsigned short s0 = sorted_src[g0];
                int pe = g0 + pc;
                for (int p = g0 + c; p < pe; p++) sorted_src[p] = s0;
            }
        }
        return;
    }
    ab_body(blockIdx.x - NB, tid, h, bns, g, bb, w1, b1, A, Bb, scale, shift, cab);
}

// ============ plain ab kernel (blocks 1 and 2) ============
__global__ __launch_bounds__(256, 4) void ab_mfma_kernel(
        const unsigned short* __restrict__ h, const float* __restrict__ bns,
        const float* __restrict__ g, const float* __restrict__ bb,
        const float* __restrict__ w1, const float* __restrict__ b1,
        unsigned short* __restrict__ A, unsigned short* __restrict__ Bb) {
    __shared__ float scale[64], shift[64], cab[128];
    ab_body(blockIdx.x, threadIdx.x, h, bns, g, bb, w1, b1, A, Bb, scale, shift, cab);
}

// ============ EdgeConv: R5 coalesced gather + CROSS-NODE B-load pipeline (R9) ============
// R7/R8 post-mortem: occupancy is a dead axis (true VGPR+AGPR footprint ~100 -> any bound
// >4 blocks/CU spills; R8's VGPR_Count=40 + 500MB FETCH = scratch). At (256,4) the cap is
// 128 and we use ~100: extra VGPRs are FREE. VALUBusy 39% ~ single-wave duty => waves are
// not covering each other; the per-node vmcnt stall (B-load issued and immediately consumed
// by ds_write) is the wall. R17's metadata-only prefetch was neutral BECAUSE it never
// prefetched the B-rows. R9: 3-deep rotating pipeline -- while computing node n, node n+S's
// B-rows (tiles 0..2, covers 99.8% of Poisson(32) degrees) are in flight into registers;
// their sidx was issued one iteration earlier; metadata two ahead. The ds_write's vmcnt
// then references loads issued a full iteration (~850cy) ago -> hidden.
// Spill sentinel: FETCH must stay ~56MB, VGPR_Count <= 128.
__global__ __launch_bounds__(256, 4) void edge_mfma_kernel(
        const unsigned short* __restrict__ A, const unsigned short* __restrict__ Bb,
        const int* __restrict__ row_start, const int* __restrict__ cnt,
        const unsigned short* __restrict__ sorted_src,
        const float* __restrict__ w2, const float* __restrict__ b2,
        unsigned short* __restrict__ catp, float* __restrict__ bnsNext) {
    __shared__ float r1[4][64], r2[4][64];
    __shared__ unsigned short stage[4][3][1024];   // [wave][buf][2KB tile]
    int tid = threadIdx.x, lane = tid & 63, wid = tid >> 6;
    int q = lane >> 4;
    int cl = lane & 15;
    int kq = q * 8;

    Uh bfr[2][4];
#pragma unroll
    for (int kh = 0; kh < 2; kh++)
#pragma unroll
        for (int cb = 0; cb < 4; cb++)
#pragma unroll
            for (int j = 0; j < 4; j++) {
                _Float16 w0 = (_Float16)w2[(kh * 32 + kq + 2 * j) * 64 + cb * 16 + cl];
                _Float16 w1v = (_Float16)w2[(kh * 32 + kq + 2 * j + 1) * 64 + cb * 16 + cl];
                bfr[kh][cb].h[j] = half2v{w0, w1v};
            }
    float b2j = b2[lane];
    float s1 = 0.f, s2 = 0.f;
    const half2v zeroh = {(_Float16)0.f, (_Float16)0.f};

    // staging geometry (R5): row held by 8 adjacent lanes, 16B chunk/lane (1 line/quad)
    int srow = lane >> 3;                 // 0..7
    int st   = lane & 7;                  // 16B chunk index
    int wswz = (st * 16) ^ (srow << 4);   // XOR swizzle
    int woff0 = srow * 128 + wswz;
    int woff1 = (8 + srow) * 128 + wswz;
    int rswz  = (cl & 7) << 4;
    int roff0 = cl * 128 + ((q * 16) ^ rswz);
    int roff1 = cl * 128 + ((64 + q * 16) ^ rswz);

    char* sb0 = (char*)&stage[wid][0][0];
    char* sb1 = (char*)&stage[wid][1][0];
    char* sb2 = (char*)&stage[wid][2][0];

    const int S = EDGE_GRID * 4;          // 8192: lockstep window sweep
    int n = blockIdx.x * 4 + wid;

    // ---- pipeline state ----
    int rs0 = 0, ct0 = 0;                 // meta(n)        [values ready]
    int rs1 = 0, ct1 = 0;                 // meta(n+S)      [values ready]
    int sn0 = 0, sn1 = 0, sn2 = 0, sn3 = 0, sn4 = 0, sn5 = 0;  // sidx(n+S) tiles 0..2 [in flight]
    uintx4 x0 = {0,0,0,0}, x1 = x0, y0 = x0, y1 = x0, z0 = x0, z1 = x0;  // B(n) tiles 0..2 [in flight]

    auto bload = [&](int s, uintx4& u) {
        u = *(const uintx4*)(Bb + (size_t)s * 64 + st * 8);
    };

    if (n < N_NODES) {
        rs0 = row_start[n]; ct0 = cnt[n];
        int nn = n + S;
        if (nn < N_NODES) { rs1 = row_start[nn]; ct1 = cnt[nn]; }
        int nt0 = (ct0 + 15) >> 4;
        if (nt0 > 0) { int a = sorted_src[rs0 + srow],      b = sorted_src[rs0 + 8 + srow];  bload(a, x0); bload(b, x1); }
        if (nt0 > 1) { int a = sorted_src[rs0 + 16 + srow], b = sorted_src[rs0 + 24 + srow]; bload(a, y0); bload(b, y1); }
        if (nt0 > 2) { int a = sorted_src[rs0 + 32 + srow], b = sorted_src[rs0 + 40 + srow]; bload(a, z0); bload(b, z1); }
        if (nn < N_NODES) {
            int nt1 = (ct1 + 15) >> 4;
            if (nt1 > 0) { sn0 = sorted_src[rs1 + srow];      sn1 = sorted_src[rs1 + 8 + srow]; }
            if (nt1 > 1) { sn2 = sorted_src[rs1 + 16 + srow]; sn3 = sorted_src[rs1 + 24 + srow]; }
            if (nt1 > 2) { sn4 = sorted_src[rs1 + 32 + srow]; sn5 = sorted_src[rs1 + 40 + srow]; }
        }
    }

    while (n < N_NODES) {
        int begC = rs0, cC = ct0;
        int ntC = (cC + 15) >> 4;
        int nn = n + S, nn2 = n + 2 * S;

        // 1. meta(n+2S) in flight
        int rs2 = 0, ct2 = 0;
        if (nn2 < N_NODES) { rs2 = row_start[nn2]; ct2 = cnt[nn2]; }

        // 2. A row (this node)
        const unsigned short* arow = A + (size_t)n * 64 + kq;
        Uh a0u, a1u;
        a0u.v = *(const uintx4*)(arow);
        a1u.v = *(const uintx4*)(arow + 32);

        // 3. ds_write in-flight B regs (vmcnt: loads issued a full iteration ago -> hidden)
        if (ntC > 0) { *(uintx4*)(sb0 + woff0) = x0; *(uintx4*)(sb0 + woff1) = x1; }
        if (ntC > 1) { *(uintx4*)(sb1 + woff0) = y0; *(uintx4*)(sb1 + woff1) = y1; }
        if (ntC > 2) { *(uintx4*)(sb2 + woff0) = z0; *(uintx4*)(sb2 + woff1) = z1; }

        // 4. issue next node's B loads (sidx issued last iteration -> values arrived)
        if (nn < N_NODES) {
            int nt1 = (ct1 + 15) >> 4;
            if (nt1 > 0) { bload(sn0, x0); bload(sn1, x1); }
            if (nt1 > 1) { bload(sn2, y0); bload(sn3, y1); }
            if (nt1 > 2) { bload(sn4, z0); bload(sn5, z1); }
        }

        floatx4 rmax0 = {-INFINITY, -INFINITY, -INFINITY, -INFINITY};
        floatx4 rmax1 = rmax0, rmax2 = rmax0, rmax3 = rmax0;

        auto tileLds = [&](const char* sb) {
            Uh b0u, b1u, f0, f1;
            b0u.v = *(const uintx4*)(sb + roff0);
            b1u.v = *(const uintx4*)(sb + roff1);
#pragma unroll
            for (int j = 0; j < 4; j++) {      // v_pk_add_f16 + v_pk_max_f16
                f0.h[j] = __builtin_elementwise_max(a0u.h[j] + b0u.h[j], zeroh);
                f1.h[j] = __builtin_elementwise_max(a1u.h[j] + b1u.h[j], zeroh);
            }
            floatx4 acc0 = {0.f, 0.f, 0.f, 0.f}, acc1 = acc0, acc2 = acc0, acc3 = acc0;
            acc0 = __builtin_amdgcn_mfma_f32_16x16x32_f16(f0.h8, bfr[0][0].h8, acc0, 0, 0, 0);
            acc1 = __builtin_amdgcn_mfma_f32_16x16x32_f16(f0.h8, bfr[0][1].h8, acc1, 0, 0, 0);
            acc2 = __builtin_amdgcn_mfma_f32_16x16x32_f16(f0.h8, bfr[0][2].h8, acc2, 0, 0, 0);
            acc3 = __builtin_amdgcn_mfma_f32_16x16x32_f16(f0.h8, bfr[0][3].h8, acc3, 0, 0, 0);
            acc0 = __builtin_amdgcn_mfma_f32_16x16x32_f16(f1.h8, bfr[1][0].h8, acc0, 0, 0, 0);
            acc1 = __builtin_amdgcn_mfma_f32_16x16x32_f16(f1.h8, bfr[1][1].h8, acc1, 0, 0, 0);
            acc2 = __builtin_amdgcn_mfma_f32_16x16x32_f16(f1.h8, bfr[1][2].h8, acc2, 0, 0, 0);
            acc3 = __builtin_amdgcn_mfma_f32_16x16x32_f16(f1.h8, bfr[1][3].h8, acc3, 0, 0, 0);
            rmax0 = __builtin_elementwise_max(rmax0, acc0);
            rmax1 = __builtin_elementwise_max(rmax1, acc1);
            rmax2 = __builtin_elementwise_max(rmax2, acc2);
            rmax3 = __builtin_elementwise_max(rmax3, acc3);
        };

        // 5. compute tiles 0..2 from LDS
        if (ntC > 0) tileLds(sb0);
        if (ntC > 1) tileLds(sb1);
        if (ntC > 2) tileLds(sb2);

        // 6. rare tail (nt>=4, ~0.3% of nodes): inline gather-stall path
        for (int t = 3; t < ntC; t++) {
            int pa = sorted_src[begC + t * 16 + srow];
            int pb = sorted_src[begC + t * 16 + 8 + srow];
            uintx4 u0, u1;
            bload(pa, u0); bload(pb, u1);
            *(uintx4*)(sb0 + woff0) = u0;
            *(uintx4*)(sb0 + woff1) = u1;
            tileLds(sb0);
        }

        // 7. epilogue: reduce + store
        float v0 = fmaxf(fmaxf(rmax0.x, rmax0.y), fmaxf(rmax0.z, rmax0.w));
        float v1 = fmaxf(fmaxf(rmax1.x, rmax1.y), fmaxf(rmax1.z, rmax1.w));
        float v2 = fmaxf(fmaxf(rmax2.x, rmax2.y), fmaxf(rmax2.z, rmax2.w));
        float v3 = fmaxf(fmaxf(rmax3.x, rmax3.y), fmaxf(rmax3.z, rmax3.w));
        v0 = fmaxf(v0, __shfl_xor(v0, 16)); v0 = fmaxf(v0, __shfl_xor(v0, 32));
        v1 = fmaxf(v1, __shfl_xor(v1, 16)); v1 = fmaxf(v1, __shfl_xor(v1, 32));
        v2 = fmaxf(v2, __shfl_xor(v2, 16)); v2 = fmaxf(v2, __shfl_xor(v2, 32));
        v3 = fmaxf(v3, __shfl_xor(v3, 16)); v3 = fmaxf(v3, __shfl_xor(v3, 32));
        float vs = (lane & 32) ? ((lane & 16) ? v3 : v2) : ((lane & 16) ? v1 : v0);
        float v = fmaxf(vs + b2j, 0.f);  // -inf (empty node) -> 0
        catp[(size_t)n * 64 + lane] = f2h(v);
        s1 += v; s2 += v * v;

        // 8. issue sidx(n+2S) (rs2 arrived by now: issued at step 1, ~full body ago)
        if (nn2 < N_NODES) {
            int nt2 = (ct2 + 15) >> 4;
            if (nt2 > 0) { sn0 = sorted_src[rs2 + srow];      sn1 = sorted_src[rs2 + 8 + srow]; }
            if (nt2 > 1) { sn2 = sorted_src[rs2 + 16 + srow]; sn3 = sorted_src[rs2 + 24 + srow]; }
            if (nt2 > 2) { sn4 = sorted_src[rs2 + 32 + srow]; sn5 = sorted_src[rs2 + 40 + srow]; }
        }

        // 9. rotate
        rs0 = rs1; ct0 = ct1; rs1 = rs2; ct1 = ct2;
        n = nn;
    }

    if (bnsNext) {
        r1[wid][lane] = s1; r2[wid][lane] = s2;
        __syncthreads();
        if (tid < 64) {
            float a  = r1[0][tid] + r1[1][tid] + r1[2][tid] + r1[3][tid];
            float c2 = r2[0][tid] + r2[1][tid] + r2[2][tid] + r2[3][tid];
            int sl = blockIdx.x & (NSLICE - 1);
            atomicAdd(&bnsNext[sl * 128 + tid], a);
            atomicAdd(&bnsNext[sl * 128 + 64 + tid], c2);
        }
    }
}

// ============================ fused graph mean pool + MLP head + log_softmax ============================
__global__ __launch_bounds__(192) void poolhead_kernel(const unsigned short* __restrict__ cat0,
                                                       const unsigned short* __restrict__ cat1,
                                                       const unsigned short* __restrict__ cat2,
                                                       const int* __restrict__ batch,
                                                       const float* __restrict__ fc1w,
                                                       const float* __restrict__ fc1b,
                                                       const float* __restrict__ fc2w,
                                                       const float* __restrict__ fc2b,
                                                       float* __restrict__ out) {
    __shared__ int se[2];
    __shared__ float p[192];
    __shared__ float hid[128];
    __shared__ float z[10];
    __shared__ float lse;
    int g = blockIdx.x, tid = threadIdx.x;  // 192 threads
    if (tid < 2) {
        int target = g + tid;
        int lo = 0, hi = N_NODES;
        while (lo < hi) { int mid = (lo + hi) >> 1; if (batch[mid] < target) lo = mid + 1; else hi = mid; }
        se[tid] = lo;
    }
    __syncthreads();
    int s = se[0], e = se[1];
    const unsigned short* plane = (tid < 64) ? cat0 : ((tid < 128) ? cat1 : cat2);
    int col = tid & 63;
    float a0 = 0.f, a1 = 0.f, a2 = 0.f, a3 = 0.f;   // 4-way ILP in the pooling loop
    int r = s;
    for (; r + 4 <= e; r += 4) {
        a0 += h2f(plane[(size_t)(r + 0) * 64 + col]);
        a1 += h2f(plane[(size_t)(r + 1) * 64 + col]);
        a2 += h2f(plane[(size_t)(r + 2) * 64 + col]);
        a3 += h2f(plane[(size_t)(r + 3) * 64 + col]);
    }
    for (; r < e; r++) a0 += h2f(plane[(size_t)r * 64 + col]);
    float acc = (a0 + a1) + (a2 + a3);
    float denom = (e > s) ? (float)(e - s) : 1.0f;
    p[tid] = acc / denom;
    __syncthreads();
    if (tid < MLP_DIM) {
        float a = fc1b[tid];
        for (int k = 0; k < 192; k++) a = fmaf(p[k], fc1w[k * 128 + tid], a);
        hid[tid] = fmaxf(a, 0.f);
    }
    __syncthreads();
    if (tid < N_CLASSES) {
        float a = fc2b[tid];
        for (int k = 0; k < 128; k++) a = fmaf(hid[k], fc2w[k * 10 + tid], a);
        z[tid] = a;
    }
    __syncthreads();
    if (tid == 0) {
        float m = z[0];
        for (int i = 1; i < 10; i++) m = fmaxf(m, z[i]);
        float sm = 0.f;
        for (int i = 0; i < 10; i++) sm += expf(z[i] - m);
        lse = m + logf(sm);
    }
    __syncthreads();
    if (tid < N_CLASSES) out[g * 10 + tid] = z[tid] - lse;
}

// ============================ launch ============================
extern "C" void kernel_launch(void* const* d_in, const int* in_sizes, int n_in,
                              void* d_out, int out_size, void* d_ws, size_t ws_size,
                              hipStream_t stream) {
    (void)in_sizes; (void)n_in; (void)out_size; (void)ws_size;
    const float* x    = (const float*)d_in[0];
    const int*   ei   = (const int*)d_in[1];
    const int*   batch= (const int*)d_in[2];
    const float* fc0w = (const float*)d_in[3];
    const float* fc0b = (const float*)d_in[4];
    const float* fc1w = (const float*)d_in[5];
    const float* fc1b = (const float*)d_in[6];
    const float* fc2w = (const float*)d_in[7];
    const float* fc2b = (const float*)d_in[8];
    const int* src = ei;
    const int* dst = ei + N_EDGES;
    float* out = (float*)d_out;

    char* w = (char*)d_ws;
    size_t off = 0;
    auto alloc = [&](size_t bytes) -> void* {
        void* p = w + off;
        off = (off + bytes + 255) & ~(size_t)255;
        return p;
    };
    const size_t MAX_PAD_EDGES = (size_t)N_EDGES + 16 * (size_t)N_NODES;

    // zeroed-every-launch block: gcur[NB] | gtotal | bns[3][NSLICE][128]
    const size_t BNS_OFF = 1280;
    const size_t ZBYTES  = BNS_OFF + 3 * NSLICE * 128 * 4;
    char* zbase = (char*)alloc(ZBYTES);
    int*   gcur   = (int*)zbase;                     // NB ints (bucket cursors = final counts)
    int*   gtotal = (int*)(zbase + 1024);            // sort2 ticket
    float* bnsAll = (float*)(zbase + BNS_OFF);       // 3 * NSLICE * 128 floats

    unsigned short* cat0 = (unsigned short*)alloc((size_t)N_NODES * 64 * 2);  // 6.4 MB/plane (f16)
    unsigned short* cat1 = (unsigned short*)alloc((size_t)N_NODES * 64 * 2);
    unsigned short* cat2 = (unsigned short*)alloc((size_t)N_NODES * 64 * 2);
    unsigned short* h0   = (unsigned short*)alloc((size_t)N_NODES * 64 * 2);
    unsigned short* Ae   = (unsigned short*)alloc((size_t)N_NODES * 64 * 2);
    unsigned short* Be   = (unsigned short*)alloc((size_t)N_NODES * 64 * 2);
    unsigned* keys = (unsigned*)alloc((size_t)NB * CAPB * 4);    // 12.85 MB
    unsigned short* sorted_src = (unsigned short*)alloc(MAX_PAD_EDGES * 2);  // 4.8 MB
    int*   cnt       = (int*)alloc((size_t)N_NODES * 4);   // plain-written in sort2
    int*   row_start = (int*)alloc((size_t)N_NODES * 4);

    (void)hipMemsetAsync(zbase, 0, ZBYTES, stream);

    // D1: pass1 + fc0 fused (independent; pass1 hides under fc0)
    fc0_pass1_kernel<<<NPASS1 + NFC0, 256, 0, stream>>>(src, dst, gcur, keys,
                                                        x, fc0w, fc0b, h0, bnsAll);
    // D2: sort-finish (hist+scan+ticket+LDS-scatter+coalesced-out) + ab(block 0) fused
    sort2_ab_kernel<<<NB + NFC0, 256, 0, stream>>>(
        keys, gcur, cnt, gtotal, row_start, sorted_src,
        h0, bnsAll,
        (const float*)d_in[9], (const float*)d_in[10],
        (const float*)d_in[11], (const float*)d_in[12], Ae, Be);

    unsigned short* planes[3] = {cat0, cat1, cat2};
    for (int blk = 0; blk < 3; blk++) {
        const float* w2 = (const float*)d_in[13 + 6 * blk];
        const float* b2 = (const float*)d_in[14 + 6 * blk];
        if (blk > 0) {
            ab_mfma_kernel<<<NFC0, 256, 0, stream>>>(
                planes[blk - 1], bnsAll + blk * NSLICE * 128,
                (const float*)d_in[9 + 6 * blk], (const float*)d_in[10 + 6 * blk],
                (const float*)d_in[11 + 6 * blk], (const float*)d_in[12 + 6 * blk], Ae, Be);
        }
        edge_mfma_kernel<<<EDGE_GRID, 256, 0, stream>>>(
            Ae, Be, row_start, cnt, sorted_src, w2, b2, planes[blk],
            (blk < 2) ? (bnsAll + (blk + 1) * NSLICE * 128) : nullptr);
    }

    poolhead_kernel<<<N_GRAPHS, 192, 0, stream>>>(cat0, cat1, cat2, batch,
                                                  fc1w, fc1b, fc2w, fc2b, out);
}

// Round 10
// 365.795 us; speedup vs baseline: 2.8462x; 1.1982x over previous
//
#include <hip/hip_runtime.h>
#include <math.h>

#define N_NODES 50000
#define N_TILES 3125      // N_NODES / 16 exactly
#define N_EDGES 1600000
#define F_IN 128
#define C 64
#define EF 64
#define N_GRAPHS 512
#define MLP_DIM 128
#define N_CLASSES 10
#define EPS 1e-5f
#define NB 196            // coarse buckets: dst>>8, 256 nodes each
#define CAPB 16384        // fixed bucket capacity (mean 8192, std ~90 -> safe)
#define CHUNK 4096        // edges per pass-1 block
#define NPASS1 391        // ceil(N_EDGES / CHUNK)
#define NFC0 782          // fc0 / ab MFMA blocks
#define NSLICE 8          // bn-stat atomic slices
#define EDGE_GRID 2048

typedef __attribute__((ext_vector_type(8))) _Float16 half8;
typedef __attribute__((ext_vector_type(2))) _Float16 half2v;
typedef __attribute__((ext_vector_type(4))) float floatx4;
typedef __attribute__((ext_vector_type(4))) unsigned uintx4;

union Uh { uintx4 v; half2v h[4]; half8 h8; };

__device__ __forceinline__ unsigned short f2h(float a) {
    union { _Float16 f; unsigned short u; } c;
    c.f = (_Float16)a;   // RNE
    return c.u;
}
__device__ __forceinline__ float h2f(unsigned short u) {
    union { unsigned short u; _Float16 f; } c;
    c.u = u;
    return (float)c.f;
}
__device__ __forceinline__ half2v pk2(float a, float b) {
    auto t = __builtin_amdgcn_cvt_pkrtz(a, b);   // __fp16 vec2 -> bit-cast (R6 lesson)
    union { decltype(t) i; half2v o; } c;
    c.i = t;
    return c.o;
}

// ============ FUSED: pass1 (blocks 0..NPASS1-1) + fc0 MFMA (blocks NPASS1..) ============
__global__ __launch_bounds__(256, 3) void fc0_pass1_kernel(
        const int* __restrict__ src, const int* __restrict__ dst,
        int* __restrict__ gcur, unsigned* __restrict__ keys,
        const float* __restrict__ x, const float* __restrict__ w,
        const float* __restrict__ b, unsigned short* __restrict__ h0,
        float* __restrict__ bns) {
    __shared__ int lcnt[NB], lbase[NB], lcnt2[NB];
    __shared__ float bl1[4][64], bl2[4][64];
    int tid = threadIdx.x;

    if (blockIdx.x < NPASS1) {
        // ---------------- pass1: bin edges into fixed-capacity buckets ----------------
        int e0 = blockIdx.x * CHUNK;
        unsigned k[CHUNK / 256];
        int bk[CHUNK / 256];
        for (int i = tid; i < NB; i += 256) lcnt[i] = 0;
        __syncthreads();
#pragma unroll
        for (int i = 0; i < CHUNK / 256; i++) {
            int e = e0 + i * 256 + tid;
            if (e < N_EDGES) {
                int d = dst[e];
                k[i] = ((unsigned)d << 16) | (unsigned)src[e];
                bk[i] = d >> 8;
                atomicAdd(&lcnt[bk[i]], 1);
            } else bk[i] = -1;
        }
        __syncthreads();
        for (int i = tid; i < NB; i += 256) {
            int c = lcnt[i];
            lbase[i] = c ? atomicAdd(&gcur[i], c) : 0;
            lcnt2[i] = 0;
        }
        __syncthreads();
#pragma unroll
        for (int i = 0; i < CHUNK / 256; i++) {
            if (bk[i] >= 0) {
                int r = atomicAdd(&lcnt2[bk[i]], 1);
                keys[(size_t)bk[i] * CAPB + lbase[bk[i]] + r] = k[i];
            }
        }
        return;
    }

    // ---------------- fc0: h0[16-node tile] = x @ fc0_w + b (f16) + BN stats ----------------
    int bid = blockIdx.x - NPASS1;
    int lane = tid & 63, wid = tid >> 6;
    int q = lane >> 4, cl = lane & 15, kq = q * 8;

    Uh wf[4][4];
#pragma unroll
    for (int kh = 0; kh < 4; kh++)
#pragma unroll
        for (int cb = 0; cb < 4; cb++)
#pragma unroll
            for (int j = 0; j < 4; j++) {
                int k0 = kh * 32 + kq + 2 * j;
                int col = cb * 16 + cl;
                wf[kh][cb].h[j] = pk2(w[k0 * 64 + col], w[(k0 + 1) * 64 + col]);
            }
    float bv[4];
#pragma unroll
    for (int cb = 0; cb < 4; cb++) bv[cb] = b[cb * 16 + cl];
    float s1[4] = {0, 0, 0, 0}, s2[4] = {0, 0, 0, 0};

    for (int t = bid * 4 + wid; t < N_TILES; t += NFC0 * 4) {
        int nb = t * 16;
        floatx4 acc[4] = {{0,0,0,0},{0,0,0,0},{0,0,0,0},{0,0,0,0}};
#pragma unroll
        for (int kh = 0; kh < 4; kh++) {
            const float* xr = x + (size_t)(nb + cl) * F_IN + kh * 32 + kq;
            floatx4 xa = *(const floatx4*)xr;
            floatx4 xb = *(const floatx4*)(xr + 4);
            Uh xf;
            xf.h[0] = pk2(xa.x, xa.y); xf.h[1] = pk2(xa.z, xa.w);
            xf.h[2] = pk2(xb.x, xb.y); xf.h[3] = pk2(xb.z, xb.w);
#pragma unroll
            for (int cb = 0; cb < 4; cb++)
                acc[cb] = __builtin_amdgcn_mfma_f32_16x16x32_f16(xf.h8, wf[kh][cb].h8, acc[cb], 0, 0, 0);
        }
#pragma unroll
        for (int cb = 0; cb < 4; cb++)
#pragma unroll
            for (int r = 0; r < 4; r++) {
                float v = acc[cb][r] + bv[cb];            // node = nb+q*4+r, col = cb*16+cl
                h0[(size_t)(nb + q * 4 + r) * 64 + cb * 16 + cl] = f2h(v);
                s1[cb] += v; s2[cb] += v * v;
            }
    }
#pragma unroll
    for (int cb = 0; cb < 4; cb++) {
        s1[cb] += __shfl_xor(s1[cb], 16); s1[cb] += __shfl_xor(s1[cb], 32);
        s2[cb] += __shfl_xor(s2[cb], 16); s2[cb] += __shfl_xor(s2[cb], 32);
    }
    if (lane < 16) {
#pragma unroll
        for (int cb = 0; cb < 4; cb++) { bl1[wid][cb * 16 + lane] = s1[cb]; bl2[wid][cb * 16 + lane] = s2[cb]; }
    }
    __syncthreads();
    if (tid < 64) {
        float a  = bl1[0][tid] + bl1[1][tid] + bl1[2][tid] + bl1[3][tid];
        float c2 = bl2[0][tid] + bl2[1][tid] + bl2[2][tid] + bl2[3][tid];
        int sl = bid & (NSLICE - 1);
        atomicAdd(&bns[sl * 128 + tid], a);
        atomicAdd(&bns[sl * 128 + 64 + tid], c2);
    }
}

// ============ ab body (device): A = bn(h)@WA + cA, B = bn(h)@WB + cB (both f16) ============
__device__ __forceinline__ void ab_body(int bid, int tid,
                                        const unsigned short* __restrict__ h,
                                        const float* __restrict__ bns,
                                        const float* __restrict__ g,
                                        const float* __restrict__ bb,
                                        const float* __restrict__ w1,
                                        const float* __restrict__ b1,
                                        unsigned short* __restrict__ A,
                                        unsigned short* __restrict__ Bb,
                                        float* scale, float* shift, float* cab) {
    int lane = tid & 63, wid = tid >> 6;
    int q = lane >> 4, cl = lane & 15, kq = q * 8;

    if (tid < 64) {
        float s1v = 0.f, s2v = 0.f;
#pragma unroll
        for (int s = 0; s < NSLICE; s++) { s1v += bns[s * 128 + tid]; s2v += bns[s * 128 + 64 + tid]; }
        float mu  = s1v * (1.0f / N_NODES);
        float var = s2v * (1.0f / N_NODES) - mu * mu;
        float sc  = g[tid] * rsqrtf(var + EPS);
        scale[tid] = sc;
        shift[tid] = bb[tid] - mu * sc;
    }
    __syncthreads();
    if (tid < 128) {
        int j = tid & 63;
        float acc = (tid < 64) ? b1[j] : 0.f;
        for (int k = 0; k < 64; k++) {
            float wa_ = w1[k * EF + j], wb_ = w1[(64 + k) * EF + j];
            acc = fmaf(shift[k], (tid < 64) ? (wa_ - wb_) : wb_, acc);
        }
        cab[tid] = acc;
    }
    Uh wa[2][4], wb[2][4];
#pragma unroll
    for (int kh = 0; kh < 2; kh++)
#pragma unroll
        for (int cb = 0; cb < 4; cb++)
#pragma unroll
            for (int j = 0; j < 4; j++) {
                int k0 = kh * 32 + kq + 2 * j;
                int col = cb * 16 + cl;
                float sa = scale[k0], sb = scale[k0 + 1];
                float a0 = w1[k0 * EF + col], b0 = w1[(64 + k0) * EF + col];
                float a1 = w1[(k0 + 1) * EF + col], b1v = w1[(64 + k0 + 1) * EF + col];
                wa[kh][cb].h[j] = pk2(sa * (a0 - b0), sb * (a1 - b1v));
                wb[kh][cb].h[j] = pk2(sa * b0, sb * b1v);
            }
    __syncthreads();
    float cav[4], cbv[4];
#pragma unroll
    for (int cb = 0; cb < 4; cb++) { cav[cb] = cab[cb * 16 + cl]; cbv[cb] = cab[64 + cb * 16 + cl]; }

    for (int t = bid * 4 + wid; t < N_TILES; t += NFC0 * 4) {
        int nb = t * 16;
        const unsigned short* hrow = h + (size_t)(nb + cl) * 64 + kq;
        Uh h0f, h1f;
        h0f.v = *(const uintx4*)hrow;
        h1f.v = *(const uintx4*)(hrow + 32);
        floatx4 accA[4] = {{0,0,0,0},{0,0,0,0},{0,0,0,0},{0,0,0,0}};
        floatx4 accB[4] = {{0,0,0,0},{0,0,0,0},{0,0,0,0},{0,0,0,0}};
#pragma unroll
        for (int cb = 0; cb < 4; cb++) {
            accA[cb] = __builtin_amdgcn_mfma_f32_16x16x32_f16(h0f.h8, wa[0][cb].h8, accA[cb], 0, 0, 0);
            accB[cb] = __builtin_amdgcn_mfma_f32_16x16x32_f16(h0f.h8, wb[0][cb].h8, accB[cb], 0, 0, 0);
            accA[cb] = __builtin_amdgcn_mfma_f32_16x16x32_f16(h1f.h8, wa[1][cb].h8, accA[cb], 0, 0, 0);
            accB[cb] = __builtin_amdgcn_mfma_f32_16x16x32_f16(h1f.h8, wb[1][cb].h8, accB[cb], 0, 0, 0);
        }
#pragma unroll
        for (int cb = 0; cb < 4; cb++)
#pragma unroll
            for (int r = 0; r < 4; r++) {
                size_t o = (size_t)(nb + q * 4 + r) * 64 + cb * 16 + cl;
                A[o]  = f2h(accA[cb][r] + cav[cb]);
                Bb[o] = f2h(accB[cb][r] + cbv[cb]);
            }
    }
}

// ==== FUSED: sort-finish (blocks 0..NB-1: hist+scan+ticket+scatter+fill per bucket) + ab0 ====
__global__ __launch_bounds__(256, 4) void sort2_ab_kernel(
        const unsigned* __restrict__ keys, const int* __restrict__ bcnt,
        int* __restrict__ cnt, int* __restrict__ gtotal,
        int* __restrict__ row_start, unsigned short* __restrict__ sorted_src,
        const unsigned short* __restrict__ h, const float* __restrict__ bns,
        const float* __restrict__ g, const float* __restrict__ bb,
        const float* __restrict__ w1, const float* __restrict__ b1,
        unsigned short* __restrict__ A, unsigned short* __restrict__ Bb) {
    __shared__ int lc[256], loc[256], rs[256], cur[256];
    __shared__ int base;
    __shared__ float scale[64], shift[64], cab[128];
    int tid = threadIdx.x;
    if (blockIdx.x < NB) {
        int b = blockIdx.x;
        lc[tid] = 0;
        cur[tid] = 0;
        __syncthreads();
        int beg = b * CAPB, end = beg + bcnt[b];
        const unsigned* kb = keys + beg;
        int nk = end - beg;
        for (int p = tid; p < nk; p += 256)
            atomicAdd(&lc[(kb[p] >> 16) & 255], 1);
        __syncthreads();
        int node = b * 256 + tid;
        int c = lc[tid];
        if (node < N_NODES) cnt[node] = c;          // plain write — no global atomics
        int pc = (c + 15) & ~15;
        loc[tid] = pc;
        __syncthreads();
        for (int off = 1; off < 256; off <<= 1) {
            int t = (tid >= off) ? loc[tid - off] : 0;
            __syncthreads();
            loc[tid] += t;
            __syncthreads();
        }
        if (tid == 255) base = atomicAdd(gtotal, loc[255]);   // ticket: order-free CSR
        __syncthreads();
        int myrs = base + loc[tid] - pc;
        rs[tid] = myrs;
        if (node < N_NODES) row_start[node] = myrs;
        __syncthreads();
        for (int p = tid; p < nk; p += 256) {
            unsigned k = kb[p];
            int lidx = (k >> 16) & 255;
            int r = atomicAdd(&cur[lidx], 1);
            sorted_src[rs[lidx] + r] = (unsigned short)(k & 0xFFFFu);
        }
        __syncthreads();
        if (node < N_NODES && c > 0) {
            unsigned short s0 = sorted_src[myrs];
            int pe = myrs + pc;
            for (int p = myrs + c; p < pe; p++) sorted_src[p] = s0;  // max idempotent
        }
        return;
    }
    ab_body(blockIdx.x - NB, tid, h, bns, g, bb, w1, b1, A, Bb, scale, shift, cab);
}

// ============ plain ab kernel (blocks 1 and 2) ============
__global__ __launch_bounds__(256, 4) void ab_mfma_kernel(
        const unsigned short* __restrict__ h, const float* __restrict__ bns,
        const float* __restrict__ g, const float* __restrict__ bb,
        const float* __restrict__ w1, const float* __restrict__ b1,
        unsigned short* __restrict__ A, unsigned short* __restrict__ Bb) {
    __shared__ float scale[64], shift[64], cab[128];
    ab_body(blockIdx.x, threadIdx.x, h, bns, g, bb, w1, b1, A, Bb, scale, shift, cab);
}

// ============ EdgeConv: R0 structure + COALESCED gather via wave-private LDS staging ============
// R5 (WIN, -12%, best measured 355.99us total): quad-coalesced B-row staging (8 adjacent
// lanes x 16B -> 1 line/quad, 32 req/tile vs 128), wave-private LDS, XOR swizzle ->
// conflict-free ds_read_b128. Request rate was the wall. CLOSED AXES (R7/R8/R9): occupancy
// >4 blocks/CU spills (true VGPR+AGPR ~100/128); cross-iteration register pipelines spill
// (R9: WRITE 7->125MB scratch); latency prefetch neutral (R17); nt-hints negative (R3/R4).
__global__ __launch_bounds__(256, 4) void edge_mfma_kernel(
        const unsigned short* __restrict__ A, const unsigned short* __restrict__ Bb,
        const int* __restrict__ row_start, const int* __restrict__ cnt,
        const unsigned short* __restrict__ sorted_src,
        const float* __restrict__ w2, const float* __restrict__ b2,
        unsigned short* __restrict__ catp, float* __restrict__ bnsNext) {
    __shared__ float r1[4][64], r2[4][64];
    __shared__ unsigned short stage[4][2][1024];   // [wave][buf][2KB tile]
    int tid = threadIdx.x, lane = tid & 63, wid = tid >> 6;
    int q = lane >> 4;
    int cl = lane & 15;
    int kq = q * 8;

    Uh bfr[2][4];
#pragma unroll
    for (int kh = 0; kh < 2; kh++)
#pragma unroll
        for (int cb = 0; cb < 4; cb++)
#pragma unroll
            for (int j = 0; j < 4; j++) {
                _Float16 w0 = (_Float16)w2[(kh * 32 + kq + 2 * j) * 64 + cb * 16 + cl];
                _Float16 w1v = (_Float16)w2[(kh * 32 + kq + 2 * j + 1) * 64 + cb * 16 + cl];
                bfr[kh][cb].h[j] = half2v{w0, w1v};
            }
    float b2j = b2[lane];
    float s1 = 0.f, s2 = 0.f;
    const half2v zeroh = {(_Float16)0.f, (_Float16)0.f};

    // staging geometry: row held by 8 adjacent lanes, 16B chunk per lane (coalesced: 1 line/quad)
    int srow = lane >> 3;                 // 0..7 (row within 8-row group)
    int st   = lane & 7;                  // 16B chunk index
    int wswz = (st * 16) ^ (srow << 4);   // XOR swizzle within the 128B row
    int woff0 = srow * 128 + wswz;        // bytes, rows 0..7
    int woff1 = (8 + srow) * 128 + wswz;  // bytes, rows 8..15
    // fragment-read offsets (row=cl): source byte X of row stored at X^((row&7)<<4)
    int rswz  = (cl & 7) << 4;
    int roff0 = cl * 128 + ((q * 16) ^ rswz);
    int roff1 = cl * 128 + ((64 + q * 16) ^ rswz);

    char* mystage0 = (char*)&stage[wid][0][0];
    char* mystage1 = (char*)&stage[wid][1][0];

    for (int n = blockIdx.x * 4 + wid; n < N_NODES; n += gridDim.x * 4) {
        int beg = row_start[n];
        int end = beg + ((cnt[n] + 15) & ~15);
        const unsigned short* arow = A + (size_t)n * 64 + kq;
        Uh a0u, a1u;
        a0u.v = *(const uintx4*)(arow);
        a1u.v = *(const uintx4*)(arow + 32);
        floatx4 rmax0 = {-INFINITY, -INFINITY, -INFINITY, -INFINITY};
        floatx4 rmax1 = rmax0, rmax2 = rmax0, rmax3 = rmax0;

        auto stageTile = [&](int p, char* sb) {
            int s0 = (int)sorted_src[p + srow];          // 8 lanes same addr -> broadcast
            int s1v = (int)sorted_src[p + 8 + srow];
            uintx4 v0 = *(const uintx4*)(Bb + (size_t)s0 * 64 + st * 8);
            uintx4 v1 = *(const uintx4*)(Bb + (size_t)s1v * 64 + st * 8);
            *(uintx4*)(sb + woff0) = v0;
            *(uintx4*)(sb + woff1) = v1;
        };
        auto tileLds = [&](const char* sb) {
            Uh b0u, b1u, f0, f1;
            b0u.v = *(const uintx4*)(sb + roff0);
            b1u.v = *(const uintx4*)(sb + roff1);
#pragma unroll
            for (int j = 0; j < 4; j++) {      // v_pk_add_f16 + v_pk_max_f16
                f0.h[j] = __builtin_elementwise_max(a0u.h[j] + b0u.h[j], zeroh);
                f1.h[j] = __builtin_elementwise_max(a1u.h[j] + b1u.h[j], zeroh);
            }
            floatx4 acc0 = {0.f, 0.f, 0.f, 0.f}, acc1 = acc0, acc2 = acc0, acc3 = acc0;
            acc0 = __builtin_amdgcn_mfma_f32_16x16x32_f16(f0.h8, bfr[0][0].h8, acc0, 0, 0, 0);
            acc1 = __builtin_amdgcn_mfma_f32_16x16x32_f16(f0.h8, bfr[0][1].h8, acc1, 0, 0, 0);
            acc2 = __builtin_amdgcn_mfma_f32_16x16x32_f16(f0.h8, bfr[0][2].h8, acc2, 0, 0, 0);
            acc3 = __builtin_amdgcn_mfma_f32_16x16x32_f16(f0.h8, bfr[0][3].h8, acc3, 0, 0, 0);
            acc0 = __builtin_amdgcn_mfma_f32_16x16x32_f16(f1.h8, bfr[1][0].h8, acc0, 0, 0, 0);
            acc1 = __builtin_amdgcn_mfma_f32_16x16x32_f16(f1.h8, bfr[1][1].h8, acc1, 0, 0, 0);
            acc2 = __builtin_amdgcn_mfma_f32_16x16x32_f16(f1.h8, bfr[1][2].h8, acc2, 0, 0, 0);
            acc3 = __builtin_amdgcn_mfma_f32_16x16x32_f16(f1.h8, bfr[1][3].h8, acc3, 0, 0, 0);
            rmax0 = __builtin_elementwise_max(rmax0, acc0);
            rmax1 = __builtin_elementwise_max(rmax1, acc1);
            rmax2 = __builtin_elementwise_max(rmax2, acc2);
            rmax3 = __builtin_elementwise_max(rmax3, acc3);
        };

        int p0 = beg;
        for (; p0 + 32 <= end; p0 += 32) {   // two tiles per iter: both staged loads in flight
            stageTile(p0, mystage0);
            stageTile(p0 + 16, mystage1);
            tileLds(mystage0);
            tileLds(mystage1);
        }
        if (p0 < end) {                       // odd-tile remainder
            stageTile(p0, mystage0);
            tileLds(mystage0);
        }

        float v0 = fmaxf(fmaxf(rmax0.x, rmax0.y), fmaxf(rmax0.z, rmax0.w));
        float v1 = fmaxf(fmaxf(rmax1.x, rmax1.y), fmaxf(rmax1.z, rmax1.w));
        float v2 = fmaxf(fmaxf(rmax2.x, rmax2.y), fmaxf(rmax2.z, rmax2.w));
        float v3 = fmaxf(fmaxf(rmax3.x, rmax3.y), fmaxf(rmax3.z, rmax3.w));
        v0 = fmaxf(v0, __shfl_xor(v0, 16)); v0 = fmaxf(v0, __shfl_xor(v0, 32));
        v1 = fmaxf(v1, __shfl_xor(v1, 16)); v1 = fmaxf(v1, __shfl_xor(v1, 32));
        v2 = fmaxf(v2, __shfl_xor(v2, 16)); v2 = fmaxf(v2, __shfl_xor(v2, 32));
        v3 = fmaxf(v3, __shfl_xor(v3, 16)); v3 = fmaxf(v3, __shfl_xor(v3, 32));
        float vs = (lane & 32) ? ((lane & 16) ? v3 : v2) : ((lane & 16) ? v1 : v0);
        float v = fmaxf(vs + b2j, 0.f);  // -inf (empty node) -> 0; folds where(isfinite)+relu
        catp[(size_t)n * 64 + lane] = f2h(v);
        s1 += v; s2 += v * v;
    }

    if (bnsNext) {
        r1[wid][lane] = s1; r2[wid][lane] = s2;
        __syncthreads();
        if (tid < 64) {
            float a  = r1[0][tid] + r1[1][tid] + r1[2][tid] + r1[3][tid];
            float c2 = r2[0][tid] + r2[1][tid] + r2[2][tid] + r2[3][tid];
            int sl = blockIdx.x & (NSLICE - 1);
            atomicAdd(&bnsNext[sl * 128 + tid], a);
            atomicAdd(&bnsNext[sl * 128 + 64 + tid], c2);
        }
    }
}

// ============================ fused graph mean pool + MLP head + log_softmax ============================
__global__ __launch_bounds__(192) void poolhead_kernel(const unsigned short* __restrict__ cat0,
                                                       const unsigned short* __restrict__ cat1,
                                                       const unsigned short* __restrict__ cat2,
                                                       const int* __restrict__ batch,
                                                       const float* __restrict__ fc1w,
                                                       const float* __restrict__ fc1b,
                                                       const float* __restrict__ fc2w,
                                                       const float* __restrict__ fc2b,
                                                       float* __restrict__ out) {
    __shared__ int se[2];
    __shared__ float p[192];
    __shared__ float hid[128];
    __shared__ float z[10];
    __shared__ float lse;
    int g = blockIdx.x, tid = threadIdx.x;  // 192 threads
    if (tid < 2) {
        int target = g + tid;
        int lo = 0, hi = N_NODES;
        while (lo < hi) { int mid = (lo + hi) >> 1; if (batch[mid] < target) lo = mid + 1; else hi = mid; }
        se[tid] = lo;
    }
    __syncthreads();
    int s = se[0], e = se[1];
    const unsigned short* plane = (tid < 64) ? cat0 : ((tid < 128) ? cat1 : cat2);
    int col = tid & 63;
    float a0 = 0.f, a1 = 0.f, a2 = 0.f, a3 = 0.f;   // 4-way ILP in the pooling loop
    int r = s;
    for (; r + 4 <= e; r += 4) {
        a0 += h2f(plane[(size_t)(r + 0) * 64 + col]);
        a1 += h2f(plane[(size_t)(r + 1) * 64 + col]);
        a2 += h2f(plane[(size_t)(r + 2) * 64 + col]);
        a3 += h2f(plane[(size_t)(r + 3) * 64 + col]);
    }
    for (; r < e; r++) a0 += h2f(plane[(size_t)r * 64 + col]);
    float acc = (a0 + a1) + (a2 + a3);
    float denom = (e > s) ? (float)(e - s) : 1.0f;
    p[tid] = acc / denom;
    __syncthreads();
    if (tid < MLP_DIM) {
        float a = fc1b[tid];
        for (int k = 0; k < 192; k++) a = fmaf(p[k], fc1w[k * 128 + tid], a);
        hid[tid] = fmaxf(a, 0.f);
    }
    __syncthreads();
    if (tid < N_CLASSES) {
        float a = fc2b[tid];
        for (int k = 0; k < 128; k++) a = fmaf(hid[k], fc2w[k * 10 + tid], a);
        z[tid] = a;
    }
    __syncthreads();
    if (tid == 0) {
        float m = z[0];
        for (int i = 1; i < 10; i++) m = fmaxf(m, z[i]);
        float sm = 0.f;
        for (int i = 0; i < 10; i++) sm += expf(z[i] - m);
        lse = m + logf(sm);
    }
    __syncthreads();
    if (tid < N_CLASSES) out[g * 10 + tid] = z[tid] - lse;
}

// ============================ launch ============================
extern "C" void kernel_launch(void* const* d_in, const int* in_sizes, int n_in,
                              void* d_out, int out_size, void* d_ws, size_t ws_size,
                              hipStream_t stream) {
    (void)in_sizes; (void)n_in; (void)out_size; (void)ws_size;
    const float* x    = (const float*)d_in[0];
    const int*   ei   = (const int*)d_in[1];
    const int*   batch= (const int*)d_in[2];
    const float* fc0w = (const float*)d_in[3];
    const float* fc0b = (const float*)d_in[4];
    const float* fc1w = (const float*)d_in[5];
    const float* fc1b = (const float*)d_in[6];
    const float* fc2w = (const float*)d_in[7];
    const float* fc2b = (const float*)d_in[8];
    const int* src = ei;
    const int* dst = ei + N_EDGES;
    float* out = (float*)d_out;

    char* w = (char*)d_ws;
    size_t off = 0;
    auto alloc = [&](size_t bytes) -> void* {
        void* p = w + off;
        off = (off + bytes + 255) & ~(size_t)255;
        return p;
    };
    const size_t MAX_PAD_EDGES = (size_t)N_EDGES + 16 * (size_t)N_NODES;

    // zeroed-every-launch block: gcur[NB] | gtotal | bns[3][NSLICE][128]
    const size_t BNS_OFF = 1280;
    const size_t ZBYTES  = BNS_OFF + 3 * NSLICE * 128 * 4;
    char* zbase = (char*)alloc(ZBYTES);
    int*   gcur   = (int*)zbase;                     // NB ints (bucket cursors = final counts)
    int*   gtotal = (int*)(zbase + 1024);            // sort2 ticket
    float* bnsAll = (float*)(zbase + BNS_OFF);       // 3 * NSLICE * 128 floats

    unsigned short* cat0 = (unsigned short*)alloc((size_t)N_NODES * 64 * 2);  // 6.4 MB/plane (f16)
    unsigned short* cat1 = (unsigned short*)alloc((size_t)N_NODES * 64 * 2);
    unsigned short* cat2 = (unsigned short*)alloc((size_t)N_NODES * 64 * 2);
    unsigned short* h0   = (unsigned short*)alloc((size_t)N_NODES * 64 * 2);
    unsigned short* Ae   = (unsigned short*)alloc((size_t)N_NODES * 64 * 2);
    unsigned short* Be   = (unsigned short*)alloc((size_t)N_NODES * 64 * 2);
    unsigned* keys = (unsigned*)alloc((size_t)NB * CAPB * 4);    // 12.85 MB
    unsigned short* sorted_src = (unsigned short*)alloc(MAX_PAD_EDGES * 2);  // 4.8 MB
    int*   cnt       = (int*)alloc((size_t)N_NODES * 4);   // plain-written in sort2
    int*   row_start = (int*)alloc((size_t)N_NODES * 4);

    (void)hipMemsetAsync(zbase, 0, ZBYTES, stream);

    // D1: pass1 + fc0 fused (independent; pass1 hides under fc0)
    fc0_pass1_kernel<<<NPASS1 + NFC0, 256, 0, stream>>>(src, dst, gcur, keys,
                                                        x, fc0w, fc0b, h0, bnsAll);
    // D2: sort-finish (hist+scan+ticket+scatter+fill) + ab(block 0) fused
    sort2_ab_kernel<<<NB + NFC0, 256, 0, stream>>>(
        keys, gcur, cnt, gtotal, row_start, sorted_src,
        h0, bnsAll,
        (const float*)d_in[9], (const float*)d_in[10],
        (const float*)d_in[11], (const float*)d_in[12], Ae, Be);

    unsigned short* planes[3] = {cat0, cat1, cat2};
    for (int blk = 0; blk < 3; blk++) {
        const float* w2 = (const float*)d_in[13 + 6 * blk];
        const float* b2 = (const float*)d_in[14 + 6 * blk];
        if (blk > 0) {
            ab_mfma_kernel<<<NFC0, 256, 0, stream>>>(
                planes[blk - 1], bnsAll + blk * NSLICE * 128,
                (const float*)d_in[9 + 6 * blk], (const float*)d_in[10 + 6 * blk],
                (const float*)d_in[11 + 6 * blk], (const float*)d_in[12 + 6 * blk], Ae, Be);
        }
        edge_mfma_kernel<<<EDGE_GRID, 256, 0, stream>>>(
            Ae, Be, row_start, cnt, sorted_src, w2, b2, planes[blk],
            (blk < 2) ? (bnsAll + (blk + 1) * NSLICE * 128) : nullptr);
    }

    poolhead_kernel<<<N_GRAPHS, 192, 0, stream>>>(cat0, cat1, cat2, batch,
                                                  fc1w, fc1b, fc2w, fc2b, out);
}

// Round 11
// 352.721 us; speedup vs baseline: 2.9517x; 1.0371x over previous
//
#include <hip/hip_runtime.h>
#include <math.h>

#define N_NODES 50000
#define N_TILES 3125      // N_NODES / 16 exactly
#define N_EDGES 1600000
#define F_IN 128
#define C 64
#define EF 64
#define N_GRAPHS 512
#define MLP_DIM 128
#define N_CLASSES 10
#define EPS 1e-5f
#define NB 196            // coarse buckets: dst>>8, 256 nodes each
#define CAPB 16384        // fixed bucket capacity (mean 8192, std ~90 -> safe)
#define CHUNK 4096        // edges per pass-1 block
#define NPASS1 391        // ceil(N_EDGES / CHUNK)
#define NFC0 782          // fc0 / ab MFMA blocks
#define NSLICE 8          // bn-stat atomic slices
#define EDGE_GRID 2048

typedef __attribute__((ext_vector_type(8))) _Float16 half8;
typedef __attribute__((ext_vector_type(2))) _Float16 half2v;
typedef __attribute__((ext_vector_type(4))) float floatx4;
typedef __attribute__((ext_vector_type(4))) unsigned uintx4;

union Uh { uintx4 v; half2v h[4]; half8 h8; };

__device__ __forceinline__ unsigned short f2h(float a) {
    union { _Float16 f; unsigned short u; } c;
    c.f = (_Float16)a;   // RNE
    return c.u;
}
__device__ __forceinline__ float h2f(unsigned short u) {
    union { unsigned short u; _Float16 f; } c;
    c.u = u;
    return (float)c.f;
}
__device__ __forceinline__ half2v pk2(float a, float b) {
    auto t = __builtin_amdgcn_cvt_pkrtz(a, b);   // __fp16 vec2 -> bit-cast (R6 lesson)
    union { decltype(t) i; half2v o; } c;
    c.i = t;
    return c.o;
}

// ============ FUSED: pass1 (blocks 0..NPASS1-1) + fc0 MFMA (blocks NPASS1..) ============
// R11: h0 tile store repacked through wave-private LDS (16 scattered 2B-store insts with
// 4x line-touch amplification -> 2 contiguous 1KB store insts). Same request-rate lever
// as R5's gather win, mirrored for stores. Wave-private: no barrier (R5 precedent).
__global__ __launch_bounds__(256, 3) void fc0_pass1_kernel(
        const int* __restrict__ src, const int* __restrict__ dst,
        int* __restrict__ gcur, unsigned* __restrict__ keys,
        const float* __restrict__ x, const float* __restrict__ w,
        const float* __restrict__ b, unsigned short* __restrict__ h0,
        float* __restrict__ bns) {
    __shared__ int lcnt[NB], lbase[NB], lcnt2[NB];
    __shared__ float bl1[4][64], bl2[4][64];
    __shared__ unsigned short hstage[4][1024];   // per-wave 2KB repack tile
    int tid = threadIdx.x;

    if (blockIdx.x < NPASS1) {
        // ---------------- pass1: bin edges into fixed-capacity buckets ----------------
        int e0 = blockIdx.x * CHUNK;
        unsigned k[CHUNK / 256];
        int bk[CHUNK / 256];
        for (int i = tid; i < NB; i += 256) lcnt[i] = 0;
        __syncthreads();
#pragma unroll
        for (int i = 0; i < CHUNK / 256; i++) {
            int e = e0 + i * 256 + tid;
            if (e < N_EDGES) {
                int d = dst[e];
                k[i] = ((unsigned)d << 16) | (unsigned)src[e];
                bk[i] = d >> 8;
                atomicAdd(&lcnt[bk[i]], 1);
            } else bk[i] = -1;
        }
        __syncthreads();
        for (int i = tid; i < NB; i += 256) {
            int c = lcnt[i];
            lbase[i] = c ? atomicAdd(&gcur[i], c) : 0;
            lcnt2[i] = 0;
        }
        __syncthreads();
#pragma unroll
        for (int i = 0; i < CHUNK / 256; i++) {
            if (bk[i] >= 0) {
                int r = atomicAdd(&lcnt2[bk[i]], 1);
                keys[(size_t)bk[i] * CAPB + lbase[bk[i]] + r] = k[i];
            }
        }
        return;
    }

    // ---------------- fc0: h0[16-node tile] = x @ fc0_w + b (f16) + BN stats ----------------
    int bid = blockIdx.x - NPASS1;
    int lane = tid & 63, wid = tid >> 6;
    int q = lane >> 4, cl = lane & 15, kq = q * 8;

    Uh wf[4][4];
#pragma unroll
    for (int kh = 0; kh < 4; kh++)
#pragma unroll
        for (int cb = 0; cb < 4; cb++)
#pragma unroll
            for (int j = 0; j < 4; j++) {
                int k0 = kh * 32 + kq + 2 * j;
                int col = cb * 16 + cl;
                wf[kh][cb].h[j] = pk2(w[k0 * 64 + col], w[(k0 + 1) * 64 + col]);
            }
    float bv[4];
#pragma unroll
    for (int cb = 0; cb < 4; cb++) bv[cb] = b[cb * 16 + cl];
    float s1[4] = {0, 0, 0, 0}, s2[4] = {0, 0, 0, 0};

    for (int t = bid * 4 + wid; t < N_TILES; t += NFC0 * 4) {
        int nb = t * 16;
        floatx4 acc[4] = {{0,0,0,0},{0,0,0,0},{0,0,0,0},{0,0,0,0}};
#pragma unroll
        for (int kh = 0; kh < 4; kh++) {
            const float* xr = x + (size_t)(nb + cl) * F_IN + kh * 32 + kq;
            floatx4 xa = *(const floatx4*)xr;
            floatx4 xb = *(const floatx4*)(xr + 4);
            Uh xf;
            xf.h[0] = pk2(xa.x, xa.y); xf.h[1] = pk2(xa.z, xa.w);
            xf.h[2] = pk2(xb.x, xb.y); xf.h[3] = pk2(xb.z, xb.w);
#pragma unroll
            for (int cb = 0; cb < 4; cb++)
                acc[cb] = __builtin_amdgcn_mfma_f32_16x16x32_f16(xf.h8, wf[kh][cb].h8, acc[cb], 0, 0, 0);
        }
        // R11 repacked store: LDS tile in (row, col) layout, then 2 contiguous 1KB stores
        unsigned short* ps = &hstage[wid][0];
#pragma unroll
        for (int cb = 0; cb < 4; cb++)
#pragma unroll
            for (int r = 0; r < 4; r++) {
                float v = acc[cb][r] + bv[cb];            // node = nb+q*4+r, col = cb*16+cl
                ps[(q * 4 + r) * 64 + cb * 16 + cl] = f2h(v);
                s1[cb] += v; s2[cb] += v * v;
            }
        {
            uintx4* d4 = (uintx4*)(h0 + (size_t)nb * 64);
            const uintx4* s4 = (const uintx4*)ps;
            d4[lane] = s4[lane];
            d4[64 + lane] = s4[64 + lane];
        }
    }
#pragma unroll
    for (int cb = 0; cb < 4; cb++) {
        s1[cb] += __shfl_xor(s1[cb], 16); s1[cb] += __shfl_xor(s1[cb], 32);
        s2[cb] += __shfl_xor(s2[cb], 16); s2[cb] += __shfl_xor(s2[cb], 32);
    }
    if (lane < 16) {
#pragma unroll
        for (int cb = 0; cb < 4; cb++) { bl1[wid][cb * 16 + lane] = s1[cb]; bl2[wid][cb * 16 + lane] = s2[cb]; }
    }
    __syncthreads();
    if (tid < 64) {
        float a  = bl1[0][tid] + bl1[1][tid] + bl1[2][tid] + bl1[3][tid];
        float c2 = bl2[0][tid] + bl2[1][tid] + bl2[2][tid] + bl2[3][tid];
        int sl = bid & (NSLICE - 1);
        atomicAdd(&bns[sl * 128 + tid], a);
        atomicAdd(&bns[sl * 128 + 64 + tid], c2);
    }
}

// ============ ab body (device): A = bn(h)@WA + cA, B = bn(h)@WB + cB (both f16) ============
// R11: A/B tile stores repacked through wave-private LDS (32 scattered 2B-store insts ->
// 4 contiguous 1KB store insts per tile). ps = per-wave 1024-ushort buffer.
__device__ __forceinline__ void ab_body(int bid, int tid,
                                        const unsigned short* __restrict__ h,
                                        const float* __restrict__ bns,
                                        const float* __restrict__ g,
                                        const float* __restrict__ bb,
                                        const float* __restrict__ w1,
                                        const float* __restrict__ b1,
                                        unsigned short* __restrict__ A,
                                        unsigned short* __restrict__ Bb,
                                        float* scale, float* shift, float* cab,
                                        unsigned short* pstage) {
    int lane = tid & 63, wid = tid >> 6;
    int q = lane >> 4, cl = lane & 15, kq = q * 8;

    if (tid < 64) {
        float s1v = 0.f, s2v = 0.f;
#pragma unroll
        for (int s = 0; s < NSLICE; s++) { s1v += bns[s * 128 + tid]; s2v += bns[s * 128 + 64 + tid]; }
        float mu  = s1v * (1.0f / N_NODES);
        float var = s2v * (1.0f / N_NODES) - mu * mu;
        float sc  = g[tid] * rsqrtf(var + EPS);
        scale[tid] = sc;
        shift[tid] = bb[tid] - mu * sc;
    }
    __syncthreads();
    if (tid < 128) {
        int j = tid & 63;
        float acc = (tid < 64) ? b1[j] : 0.f;
        for (int k = 0; k < 64; k++) {
            float wa_ = w1[k * EF + j], wb_ = w1[(64 + k) * EF + j];
            acc = fmaf(shift[k], (tid < 64) ? (wa_ - wb_) : wb_, acc);
        }
        cab[tid] = acc;
    }
    Uh wa[2][4], wb[2][4];
#pragma unroll
    for (int kh = 0; kh < 2; kh++)
#pragma unroll
        for (int cb = 0; cb < 4; cb++)
#pragma unroll
            for (int j = 0; j < 4; j++) {
                int k0 = kh * 32 + kq + 2 * j;
                int col = cb * 16 + cl;
                float sa = scale[k0], sb = scale[k0 + 1];
                float a0 = w1[k0 * EF + col], b0 = w1[(64 + k0) * EF + col];
                float a1 = w1[(k0 + 1) * EF + col], b1v = w1[(64 + k0 + 1) * EF + col];
                wa[kh][cb].h[j] = pk2(sa * (a0 - b0), sb * (a1 - b1v));
                wb[kh][cb].h[j] = pk2(sa * b0, sb * b1v);
            }
    __syncthreads();
    float cav[4], cbv[4];
#pragma unroll
    for (int cb = 0; cb < 4; cb++) { cav[cb] = cab[cb * 16 + cl]; cbv[cb] = cab[64 + cb * 16 + cl]; }

    unsigned short* ps = pstage + wid * 1024;
    for (int t = bid * 4 + wid; t < N_TILES; t += NFC0 * 4) {
        int nb = t * 16;
        const unsigned short* hrow = h + (size_t)(nb + cl) * 64 + kq;
        Uh h0f, h1f;
        h0f.v = *(const uintx4*)hrow;
        h1f.v = *(const uintx4*)(hrow + 32);
        floatx4 accA[4] = {{0,0,0,0},{0,0,0,0},{0,0,0,0},{0,0,0,0}};
        floatx4 accB[4] = {{0,0,0,0},{0,0,0,0},{0,0,0,0},{0,0,0,0}};
#pragma unroll
        for (int cb = 0; cb < 4; cb++) {
            accA[cb] = __builtin_amdgcn_mfma_f32_16x16x32_f16(h0f.h8, wa[0][cb].h8, accA[cb], 0, 0, 0);
            accB[cb] = __builtin_amdgcn_mfma_f32_16x16x32_f16(h0f.h8, wb[0][cb].h8, accB[cb], 0, 0, 0);
            accA[cb] = __builtin_amdgcn_mfma_f32_16x16x32_f16(h1f.h8, wa[1][cb].h8, accA[cb], 0, 0, 0);
            accB[cb] = __builtin_amdgcn_mfma_f32_16x16x32_f16(h1f.h8, wb[1][cb].h8, accB[cb], 0, 0, 0);
        }
        // A tile: repack in LDS, stream out contiguously
#pragma unroll
        for (int cb = 0; cb < 4; cb++)
#pragma unroll
            for (int r = 0; r < 4; r++)
                ps[(q * 4 + r) * 64 + cb * 16 + cl] = f2h(accA[cb][r] + cav[cb]);
        {
            uintx4* d4 = (uintx4*)(A + (size_t)nb * 64);
            const uintx4* s4 = (const uintx4*)ps;
            d4[lane] = s4[lane];
            d4[64 + lane] = s4[64 + lane];
        }
        // B tile: reuse the same wave-private buffer (same-wave LDS ops are in-order)
#pragma unroll
        for (int cb = 0; cb < 4; cb++)
#pragma unroll
            for (int r = 0; r < 4; r++)
                ps[(q * 4 + r) * 64 + cb * 16 + cl] = f2h(accB[cb][r] + cbv[cb]);
        {
            uintx4* d4 = (uintx4*)(Bb + (size_t)nb * 64);
            const uintx4* s4 = (const uintx4*)ps;
            d4[lane] = s4[lane];
            d4[64 + lane] = s4[64 + lane];
        }
    }
}

// ==== FUSED: sort-finish (blocks 0..NB-1: hist+scan+ticket+scatter+fill per bucket) + ab0 ====
__global__ __launch_bounds__(256, 4) void sort2_ab_kernel(
        const unsigned* __restrict__ keys, const int* __restrict__ bcnt,
        int* __restrict__ cnt, int* __restrict__ gtotal,
        int* __restrict__ row_start, unsigned short* __restrict__ sorted_src,
        const unsigned short* __restrict__ h, const float* __restrict__ bns,
        const float* __restrict__ g, const float* __restrict__ bb,
        const float* __restrict__ w1, const float* __restrict__ b1,
        unsigned short* __restrict__ A, unsigned short* __restrict__ Bb) {
    __shared__ int lc[256], loc[256], rs[256], cur[256];
    __shared__ int base;
    __shared__ float scale[64], shift[64], cab[128];
    __shared__ unsigned short pstage[4][1024];
    int tid = threadIdx.x;
    if (blockIdx.x < NB) {
        int b = blockIdx.x;
        lc[tid] = 0;
        cur[tid] = 0;
        __syncthreads();
        int beg = b * CAPB, end = beg + bcnt[b];
        const unsigned* kb = keys + beg;
        int nk = end - beg;
        for (int p = tid; p < nk; p += 256)
            atomicAdd(&lc[(kb[p] >> 16) & 255], 1);
        __syncthreads();
        int node = b * 256 + tid;
        int c = lc[tid];
        if (node < N_NODES) cnt[node] = c;          // plain write — no global atomics
        int pc = (c + 15) & ~15;
        loc[tid] = pc;
        __syncthreads();
        for (int off = 1; off < 256; off <<= 1) {
            int t = (tid >= off) ? loc[tid - off] : 0;
            __syncthreads();
            loc[tid] += t;
            __syncthreads();
        }
        if (tid == 255) base = atomicAdd(gtotal, loc[255]);   // ticket: order-free CSR
        __syncthreads();
        int myrs = base + loc[tid] - pc;
        rs[tid] = myrs;
        if (node < N_NODES) row_start[node] = myrs;
        __syncthreads();
        for (int p = tid; p < nk; p += 256) {
            unsigned k = kb[p];
            int lidx = (k >> 16) & 255;
            int r = atomicAdd(&cur[lidx], 1);
            sorted_src[rs[lidx] + r] = (unsigned short)(k & 0xFFFFu);
        }
        __syncthreads();
        if (node < N_NODES && c > 0) {
            unsigned short s0 = sorted_src[myrs];
            int pe = myrs + pc;
            for (int p = myrs + c; p < pe; p++) sorted_src[p] = s0;  // max idempotent
        }
        return;
    }
    ab_body(blockIdx.x - NB, tid, h, bns, g, bb, w1, b1, A, Bb, scale, shift, cab, &pstage[0][0]);
}

// ============ plain ab kernel (blocks 1 and 2) ============
__global__ __launch_bounds__(256, 4) void ab_mfma_kernel(
        const unsigned short* __restrict__ h, const float* __restrict__ bns,
        const float* __restrict__ g, const float* __restrict__ bb,
        const float* __restrict__ w1, const float* __restrict__ b1,
        unsigned short* __restrict__ A, unsigned short* __restrict__ Bb) {
    __shared__ float scale[64], shift[64], cab[128];
    __shared__ unsigned short pstage[4][1024];
    ab_body(blockIdx.x, threadIdx.x, h, bns, g, bb, w1, b1, A, Bb, scale, shift, cab, &pstage[0][0]);
}

// ============ EdgeConv: R0 structure + COALESCED gather via wave-private LDS staging ============
// R5 (WIN, -12%, best measured 355.99us total): quad-coalesced B-row staging (8 adjacent
// lanes x 16B -> 1 line/quad, 32 req/tile vs 128), wave-private LDS, XOR swizzle ->
// conflict-free ds_read_b128. Request rate was the wall. CLOSED AXES (R7/R8/R9): occupancy
// >4 blocks/CU spills (true VGPR+AGPR ~100/128); cross-iteration register pipelines spill
// (R9: WRITE 7->125MB scratch); latency prefetch neutral (R17); nt-hints negative (R3/R4).
__global__ __launch_bounds__(256, 4) void edge_mfma_kernel(
        const unsigned short* __restrict__ A, const unsigned short* __restrict__ Bb,
        const int* __restrict__ row_start, const int* __restrict__ cnt,
        const unsigned short* __restrict__ sorted_src,
        const float* __restrict__ w2, const float* __restrict__ b2,
        unsigned short* __restrict__ catp, float* __restrict__ bnsNext) {
    __shared__ float r1[4][64], r2[4][64];
    __shared__ unsigned short stage[4][2][1024];   // [wave][buf][2KB tile]
    int tid = threadIdx.x, lane = tid & 63, wid = tid >> 6;
    int q = lane >> 4;
    int cl = lane & 15;
    int kq = q * 8;

    Uh bfr[2][4];
#pragma unroll
    for (int kh = 0; kh < 2; kh++)
#pragma unroll
        for (int cb = 0; cb < 4; cb++)
#pragma unroll
            for (int j = 0; j < 4; j++) {
                _Float16 w0 = (_Float16)w2[(kh * 32 + kq + 2 * j) * 64 + cb * 16 + cl];
                _Float16 w1v = (_Float16)w2[(kh * 32 + kq + 2 * j + 1) * 64 + cb * 16 + cl];
                bfr[kh][cb].h[j] = half2v{w0, w1v};
            }
    float b2j = b2[lane];
    float s1 = 0.f, s2 = 0.f;
    const half2v zeroh = {(_Float16)0.f, (_Float16)0.f};

    // staging geometry: row held by 8 adjacent lanes, 16B chunk per lane (coalesced: 1 line/quad)
    int srow = lane >> 3;                 // 0..7 (row within 8-row group)
    int st   = lane & 7;                  // 16B chunk index
    int wswz = (st * 16) ^ (srow << 4);   // XOR swizzle within the 128B row
    int woff0 = srow * 128 + wswz;        // bytes, rows 0..7
    int woff1 = (8 + srow) * 128 + wswz;  // bytes, rows 8..15
    // fragment-read offsets (row=cl): source byte X of row stored at X^((row&7)<<4)
    int rswz  = (cl & 7) << 4;
    int roff0 = cl * 128 + ((q * 16) ^ rswz);
    int roff1 = cl * 128 + ((64 + q * 16) ^ rswz);

    char* mystage0 = (char*)&stage[wid][0][0];
    char* mystage1 = (char*)&stage[wid][1][0];

    for (int n = blockIdx.x * 4 + wid; n < N_NODES; n += gridDim.x * 4) {
        int beg = row_start[n];
        int end = beg + ((cnt[n] + 15) & ~15);
        const unsigned short* arow = A + (size_t)n * 64 + kq;
        Uh a0u, a1u;
        a0u.v = *(const uintx4*)(arow);
        a1u.v = *(const uintx4*)(arow + 32);
        floatx4 rmax0 = {-INFINITY, -INFINITY, -INFINITY, -INFINITY};
        floatx4 rmax1 = rmax0, rmax2 = rmax0, rmax3 = rmax0;

        auto stageTile = [&](int p, char* sb) {
            int s0 = (int)sorted_src[p + srow];          // 8 lanes same addr -> broadcast
            int s1v = (int)sorted_src[p + 8 + srow];
            uintx4 v0 = *(const uintx4*)(Bb + (size_t)s0 * 64 + st * 8);
            uintx4 v1 = *(const uintx4*)(Bb + (size_t)s1v * 64 + st * 8);
            *(uintx4*)(sb + woff0) = v0;
            *(uintx4*)(sb + woff1) = v1;
        };
        auto tileLds = [&](const char* sb) {
            Uh b0u, b1u, f0, f1;
            b0u.v = *(const uintx4*)(sb + roff0);
            b1u.v = *(const uintx4*)(sb + roff1);
#pragma unroll
            for (int j = 0; j < 4; j++) {      // v_pk_add_f16 + v_pk_max_f16
                f0.h[j] = __builtin_elementwise_max(a0u.h[j] + b0u.h[j], zeroh);
                f1.h[j] = __builtin_elementwise_max(a1u.h[j] + b1u.h[j], zeroh);
            }
            floatx4 acc0 = {0.f, 0.f, 0.f, 0.f}, acc1 = acc0, acc2 = acc0, acc3 = acc0;
            acc0 = __builtin_amdgcn_mfma_f32_16x16x32_f16(f0.h8, bfr[0][0].h8, acc0, 0, 0, 0);
            acc1 = __builtin_amdgcn_mfma_f32_16x16x32_f16(f0.h8, bfr[0][1].h8, acc1, 0, 0, 0);
            acc2 = __builtin_amdgcn_mfma_f32_16x16x32_f16(f0.h8, bfr[0][2].h8, acc2, 0, 0, 0);
            acc3 = __builtin_amdgcn_mfma_f32_16x16x32_f16(f0.h8, bfr[0][3].h8, acc3, 0, 0, 0);
            acc0 = __builtin_amdgcn_mfma_f32_16x16x32_f16(f1.h8, bfr[1][0].h8, acc0, 0, 0, 0);
            acc1 = __builtin_amdgcn_mfma_f32_16x16x32_f16(f1.h8, bfr[1][1].h8, acc1, 0, 0, 0);
            acc2 = __builtin_amdgcn_mfma_f32_16x16x32_f16(f1.h8, bfr[1][2].h8, acc2, 0, 0, 0);
            acc3 = __builtin_amdgcn_mfma_f32_16x16x32_f16(f1.h8, bfr[1][3].h8, acc3, 0, 0, 0);
            rmax0 = __builtin_elementwise_max(rmax0, acc0);
            rmax1 = __builtin_elementwise_max(rmax1, acc1);
            rmax2 = __builtin_elementwise_max(rmax2, acc2);
            rmax3 = __builtin_elementwise_max(rmax3, acc3);
        };

        int p0 = beg;
        for (; p0 + 32 <= end; p0 += 32) {   // two tiles per iter: both staged loads in flight
            stageTile(p0, mystage0);
            stageTile(p0 + 16, mystage1);
            tileLds(mystage0);
            tileLds(mystage1);
        }
        if (p0 < end) {                       // odd-tile remainder
            stageTile(p0, mystage0);
            tileLds(mystage0);
        }

        float v0 = fmaxf(fmaxf(rmax0.x, rmax0.y), fmaxf(rmax0.z, rmax0.w));
        float v1 = fmaxf(fmaxf(rmax1.x, rmax1.y), fmaxf(rmax1.z, rmax1.w));
        float v2 = fmaxf(fmaxf(rmax2.x, rmax2.y), fmaxf(rmax2.z, rmax2.w));
        float v3 = fmaxf(fmaxf(rmax3.x, rmax3.y), fmaxf(rmax3.z, rmax3.w));
        v0 = fmaxf(v0, __shfl_xor(v0, 16)); v0 = fmaxf(v0, __shfl_xor(v0, 32));
        v1 = fmaxf(v1, __shfl_xor(v1, 16)); v1 = fmaxf(v1, __shfl_xor(v1, 32));
        v2 = fmaxf(v2, __shfl_xor(v2, 16)); v2 = fmaxf(v2, __shfl_xor(v2, 32));
        v3 = fmaxf(v3, __shfl_xor(v3, 16)); v3 = fmaxf(v3, __shfl_xor(v3, 32));
        float vs = (lane & 32) ? ((lane & 16) ? v3 : v2) : ((lane & 16) ? v1 : v0);
        float v = fmaxf(vs + b2j, 0.f);  // -inf (empty node) -> 0; folds where(isfinite)+relu
        catp[(size_t)n * 64 + lane] = f2h(v);
        s1 += v; s2 += v * v;
    }

    if (bnsNext) {
        r1[wid][lane] = s1; r2[wid][lane] = s2;
        __syncthreads();
        if (tid < 64) {
            float a  = r1[0][tid] + r1[1][tid] + r1[2][tid] + r1[3][tid];
            float c2 = r2[0][tid] + r2[1][tid] + r2[2][tid] + r2[3][tid];
            int sl = blockIdx.x & (NSLICE - 1);
            atomicAdd(&bnsNext[sl * 128 + tid], a);
            atomicAdd(&bnsNext[sl * 128 + 64 + tid], c2);
        }
    }
}

// ============================ fused graph mean pool + MLP head + log_softmax ============================
__global__ __launch_bounds__(192) void poolhead_kernel(const unsigned short* __restrict__ cat0,
                                                       const unsigned short* __restrict__ cat1,
                                                       const unsigned short* __restrict__ cat2,
                                                       const int* __restrict__ batch,
                                                       const float* __restrict__ fc1w,
                                                       const float* __restrict__ fc1b,
                                                       const float* __restrict__ fc2w,
                                                       const float* __restrict__ fc2b,
                                                       float* __restrict__ out) {
    __shared__ int se[2];
    __shared__ float p[192];
    __shared__ float hid[128];
    __shared__ float z[10];
    __shared__ float lse;
    int g = blockIdx.x, tid = threadIdx.x;  // 192 threads
    if (tid < 2) {
        int target = g + tid;
        int lo = 0, hi = N_NODES;
        while (lo < hi) { int mid = (lo + hi) >> 1; if (batch[mid] < target) lo = mid + 1; else hi = mid; }
        se[tid] = lo;
    }
    __syncthreads();
    int s = se[0], e = se[1];
    const unsigned short* plane = (tid < 64) ? cat0 : ((tid < 128) ? cat1 : cat2);
    int col = tid & 63;
    float a0 = 0.f, a1 = 0.f, a2 = 0.f, a3 = 0.f;   // 4-way ILP in the pooling loop
    int r = s;
    for (; r + 4 <= e; r += 4) {
        a0 += h2f(plane[(size_t)(r + 0) * 64 + col]);
        a1 += h2f(plane[(size_t)(r + 1) * 64 + col]);
        a2 += h2f(plane[(size_t)(r + 2) * 64 + col]);
        a3 += h2f(plane[(size_t)(r + 3) * 64 + col]);
    }
    for (; r < e; r++) a0 += h2f(plane[(size_t)r * 64 + col]);
    float acc = (a0 + a1) + (a2 + a3);
    float denom = (e > s) ? (float)(e - s) : 1.0f;
    p[tid] = acc / denom;
    __syncthreads();
    if (tid < MLP_DIM) {
        float a = fc1b[tid];
        for (int k = 0; k < 192; k++) a = fmaf(p[k], fc1w[k * 128 + tid], a);
        hid[tid] = fmaxf(a, 0.f);
    }
    __syncthreads();
    if (tid < N_CLASSES) {
        float a = fc2b[tid];
        for (int k = 0; k < 128; k++) a = fmaf(hid[k], fc2w[k * 10 + tid], a);
        z[tid] = a;
    }
    __syncthreads();
    if (tid == 0) {
        float m = z[0];
        for (int i = 1; i < 10; i++) m = fmaxf(m, z[i]);
        float sm = 0.f;
        for (int i = 0; i < 10; i++) sm += expf(z[i] - m);
        lse = m + logf(sm);
    }
    __syncthreads();
    if (tid < N_CLASSES) out[g * 10 + tid] = z[tid] - lse;
}

// ============================ launch ============================
extern "C" void kernel_launch(void* const* d_in, const int* in_sizes, int n_in,
                              void* d_out, int out_size, void* d_ws, size_t ws_size,
                              hipStream_t stream) {
    (void)in_sizes; (void)n_in; (void)out_size; (void)ws_size;
    const float* x    = (const float*)d_in[0];
    const int*   ei   = (const int*)d_in[1];
    const int*   batch= (const int*)d_in[2];
    const float* fc0w = (const float*)d_in[3];
    const float* fc0b = (const float*)d_in[4];
    const float* fc1w = (const float*)d_in[5];
    const float* fc1b = (const float*)d_in[6];
    const float* fc2w = (const float*)d_in[7];
    const float* fc2b = (const float*)d_in[8];
    const int* src = ei;
    const int* dst = ei + N_EDGES;
    float* out = (float*)d_out;

    char* w = (char*)d_ws;
    size_t off = 0;
    auto alloc = [&](size_t bytes) -> void* {
        void* p = w + off;
        off = (off + bytes + 255) & ~(size_t)255;
        return p;
    };
    const size_t MAX_PAD_EDGES = (size_t)N_EDGES + 16 * (size_t)N_NODES;

    // zeroed-every-launch block: gcur[NB] | gtotal | bns[3][NSLICE][128]
    const size_t BNS_OFF = 1280;
    const size_t ZBYTES  = BNS_OFF + 3 * NSLICE * 128 * 4;
    char* zbase = (char*)alloc(ZBYTES);
    int*   gcur   = (int*)zbase;                     // NB ints (bucket cursors = final counts)
    int*   gtotal = (int*)(zbase + 1024);            // sort2 ticket
    float* bnsAll = (float*)(zbase + BNS_OFF);       // 3 * NSLICE * 128 floats

    unsigned short* cat0 = (unsigned short*)alloc((size_t)N_NODES * 64 * 2);  // 6.4 MB/plane (f16)
    unsigned short* cat1 = (unsigned short*)alloc((size_t)N_NODES * 64 * 2);
    unsigned short* cat2 = (unsigned short*)alloc((size_t)N_NODES * 64 * 2);
    unsigned short* h0   = (unsigned short*)alloc((size_t)N_NODES * 64 * 2);
    unsigned short* Ae   = (unsigned short*)alloc((size_t)N_NODES * 64 * 2);
    unsigned short* Be   = (unsigned short*)alloc((size_t)N_NODES * 64 * 2);
    unsigned* keys = (unsigned*)alloc((size_t)NB * CAPB * 4);    // 12.85 MB
    unsigned short* sorted_src = (unsigned short*)alloc(MAX_PAD_EDGES * 2);  // 4.8 MB
    int*   cnt       = (int*)alloc((size_t)N_NODES * 4);   // plain-written in sort2
    int*   row_start = (int*)alloc((size_t)N_NODES * 4);

    (void)hipMemsetAsync(zbase, 0, ZBYTES, stream);

    // D1: pass1 + fc0 fused (independent; pass1 hides under fc0)
    fc0_pass1_kernel<<<NPASS1 + NFC0, 256, 0, stream>>>(src, dst, gcur, keys,
                                                        x, fc0w, fc0b, h0, bnsAll);
    // D2: sort-finish (hist+scan+ticket+scatter+fill) + ab(block 0) fused
    sort2_ab_kernel<<<NB + NFC0, 256, 0, stream>>>(
        keys, gcur, cnt, gtotal, row_start, sorted_src,
        h0, bnsAll,
        (const float*)d_in[9], (const float*)d_in[10],
        (const float*)d_in[11], (const float*)d_in[12], Ae, Be);

    unsigned short* planes[3] = {cat0, cat1, cat2};
    for (int blk = 0; blk < 3; blk++) {
        const float* w2 = (const float*)d_in[13 + 6 * blk];
        const float* b2 = (const float*)d_in[14 + 6 * blk];
        if (blk > 0) {
            ab_mfma_kernel<<<NFC0, 256, 0, stream>>>(
                planes[blk - 1], bnsAll + blk * NSLICE * 128,
                (const float*)d_in[9 + 6 * blk], (const float*)d_in[10 + 6 * blk],
                (const float*)d_in[11 + 6 * blk], (const float*)d_in[12 + 6 * blk], Ae, Be);
        }
        edge_mfma_kernel<<<EDGE_GRID, 256, 0, stream>>>(
            Ae, Be, row_start, cnt, sorted_src, w2, b2, planes[blk],
            (blk < 2) ? (bnsAll + (blk + 1) * NSLICE * 128) : nullptr);
    }

    poolhead_kernel<<<N_GRAPHS, 192, 0, stream>>>(cat0, cat1, cat2, batch,
                                                  fc1w, fc1b, fc2w, fc2b, out);
}